// Round 5
// baseline (2392.818 us; speedup 1.0000x reference)
//
#include <hip/hip_runtime.h>

typedef _Float16 half8 __attribute__((ext_vector_type(8)));
typedef _Float16 half4 __attribute__((ext_vector_type(4)));
typedef float floatx4 __attribute__((ext_vector_type(4)));

static constexpr int BATCH = 1024;
static constexpr int NIN   = 512;    // in_features
static constexpr int MOUT  = 1024;   // out_features
static constexpr float LAMBD = 0.2f;
static constexpr float TOLF  = 1e-4f;
static constexpr int MAX_ITERS = 100;
static constexpr int MM = BATCH * MOUT;   // 1M elements

// Fragment-swizzled layout for 16x16x32 MFMA operands (A: rows, B: cols), f16:
//   flat = ((tile16*32 + kchunk32)*64 + lane)*8 + elem
//   lane = (idx&15) | (((k>>3)&3)<<4), elem = k&7
__device__ __forceinline__ size_t swz(int idx, int k) {
    return ((((size_t)(idx >> 4) * 32 + (k >> 5)) * 64 +
             ((idx & 15) | (((k >> 3) & 3) << 4))) << 3) + (k & 7);
}

__device__ __forceinline__ float shrinkf(float t) {
    float a = fabsf(t) - LAMBD;
    return a > 0.f ? copysignf(a, t) : 0.f;
}

// ---------------------------------------------------------------------------
// XCD-local 64-block SLOT barrier (contention-free). Each block stores seq to
// its own slot (relaxed, agent-scope -> L1-bypass); wave 0's 64 lanes poll all
// 64 slots with one coalesced load + ballot. No serialized RMW chain (the
// round-4 atomicAdd barrier cost ~64 queued RMWs per barrier). Visibility:
// __syncthreads drains vmcnt (write-through L1 -> stores at XCD L2) before the
// slot store; after release, L1-only invalidate. Validated coherence model
// from rounds 3/4 (same-XCD stripes, absmax 0.0).
// ---------------------------------------------------------------------------
__device__ __forceinline__ void gbar64s(int* slots, int memb, int seq) {
    __syncthreads();                       // all block stores drained to L2
    if (threadIdx.x == 0)
        __hip_atomic_store(&slots[memb], seq, __ATOMIC_RELAXED,
                           __HIP_MEMORY_SCOPE_AGENT);
    if (threadIdx.x < 64) {
        for (;;) {
            int v = __hip_atomic_load(&slots[threadIdx.x], __ATOMIC_RELAXED,
                                      __HIP_MEMORY_SCOPE_AGENT);
            if (__ballot(v >= seq) == ~0ull) break;
            __builtin_amdgcn_s_sleep(1);
        }
    }
    __syncthreads();
    asm volatile("buffer_inv sc0" ::: "memory");   // L1-only invalidate
}

// ---------------------------------------------------------------------------
// zero-init: t, enc, dec, swizzled enc halves, solved + barrier region
// ---------------------------------------------------------------------------
__global__ __launch_bounds__(256) void zero_init(float* t, float* enc,
                                                 float* dec, float* ench_f,
                                                 float* encl_f, int* solved) {
    int i = blockIdx.x * 256 + threadIdx.x;
    if (i < MM) { t[i] = 0.f; enc[i] = 0.f; }
    if (i < MM / 2) { dec[i] = 0.f; ench_f[i] = 0.f; encl_f[i] = 0.f; }
    if (i < 4096) solved[i] = 0;   // solved[0..1023] + barrier slots @ +1088
}

// ---------------------------------------------------------------------------
// Th/Tl = B-fragment-swizzled split-f16 of Minv (col=n in 1024, k in 1024).
// ---------------------------------------------------------------------------
__global__ __launch_bounds__(256) void split_minv(const float* __restrict__ Minv,
                                                  _Float16* __restrict__ Th,
                                                  _Float16* __restrict__ Tl) {
    int g = blockIdx.x * 256 + threadIdx.x;   // 131072 threads
    int n = g & 1023, k0 = (g >> 10) << 3;
    half8 h, l;
    #pragma unroll
    for (int e = 0; e < 8; ++e) {
        float val = Minv[(size_t)(k0 + e) * MOUT + n];
        _Float16 hh = (_Float16)val;
        h[e] = hh;
        l[e] = (_Float16)(val - (float)hh);
    }
    size_t off = swz(n, k0);
    *(half8*)&Th[off] = h;
    *(half8*)&Tl[off] = l;
}

// ---------------------------------------------------------------------------
// wsh/wsl = B-fragment-swizzled split-f16 of weight (col=n in 512, k in 1024).
// ---------------------------------------------------------------------------
__global__ __launch_bounds__(256) void split_w(const float* __restrict__ w,
                                               _Float16* __restrict__ wsh,
                                               _Float16* __restrict__ wsl) {
    int g = blockIdx.x * 256 + threadIdx.x;   // 65536 threads
    int n = g & 511, k0 = (g >> 9) << 3;
    half8 h, l;
    #pragma unroll
    for (int e = 0; e < 8; ++e) {
        float val = w[(size_t)(k0 + e) * NIN + n];
        _Float16 hh = (_Float16)val;
        h[e] = hh;
        l[e] = (_Float16)(val - (float)hh);
    }
    size_t off = swz(n, k0);
    *(half8*)&wsh[off] = h;
    *(half8*)&wsl[off] = l;
}

// ---------------------------------------------------------------------------
// adb = x @ w^T (fp32, once). Epilogue emits beff = adb as A-swizzled h/l.
// ---------------------------------------------------------------------------
__global__ __launch_bounds__(256) void gemm_adb(const float* __restrict__ x,
                                                const float* __restrict__ w,
                                                float* __restrict__ adb,
                                                _Float16* __restrict__ bh,
                                                _Float16* __restrict__ bl) {
    __shared__ float As[16][68];
    __shared__ float Bs[16][68];
    const int tid = threadIdx.x;
    const int i0 = (blockIdx.x >> 4) * 64, j0 = (blockIdx.x & 15) * 64;
    const int tx = tid & 15, ty = tid >> 4;
    const int lr = tid >> 2, lk = (tid & 3) << 2;
    float acc[4][4] = {};
    for (int k0 = 0; k0 < NIN; k0 += 16) {
        float4 a4 = *(const float4*)&x[(i0 + lr) * NIN + k0 + lk];
        As[lk + 0][lr] = a4.x; As[lk + 1][lr] = a4.y;
        As[lk + 2][lr] = a4.z; As[lk + 3][lr] = a4.w;
        float4 b4 = *(const float4*)&w[(j0 + lr) * NIN + k0 + lk];
        Bs[lk + 0][lr] = b4.x; Bs[lk + 1][lr] = b4.y;
        Bs[lk + 2][lr] = b4.z; Bs[lk + 3][lr] = b4.w;
        __syncthreads();
        #pragma unroll
        for (int kk = 0; kk < 16; ++kk) {
            float4 a_ = *(const float4*)&As[kk][ty << 2];
            float4 b_ = *(const float4*)&Bs[kk][tx << 2];
            #pragma unroll
            for (int r = 0; r < 4; ++r) {
                float av = r == 0 ? a_.x : r == 1 ? a_.y : r == 2 ? a_.z : a_.w;
                acc[r][0] = fmaf(av, b_.x, acc[r][0]);
                acc[r][1] = fmaf(av, b_.y, acc[r][1]);
                acc[r][2] = fmaf(av, b_.z, acc[r][2]);
                acc[r][3] = fmaf(av, b_.w, acc[r][3]);
            }
        }
        __syncthreads();
    }
    const int k4 = j0 + (tx << 2);
    #pragma unroll
    for (int r = 0; r < 4; ++r) {
        const int row = i0 + (ty << 2) + r;
        *(float4*)&adb[(size_t)row * MOUT + k4] =
            make_float4(acc[r][0], acc[r][1], acc[r][2], acc[r][3]);
        half4 h, l;
        #pragma unroll
        for (int e = 0; e < 4; ++e) {
            _Float16 hh = (_Float16)acc[r][e];
            h[e] = hh;
            l[e] = (_Float16)(acc[r][e] - (float)hh);
        }
        size_t off = swz(row, k4);
        *(half4*)&bh[off] = h;
        *(half4*)&bl[off] = l;
    }
}

// ---------------------------------------------------------------------------
// FUSED persistent ADMM loop, B-in-LDS + slot barrier + depth-3 A prefetch.
// 512 blocks (2/CU): 8 stripes (mt, 128 rows) x 32 nt (32 cols) x 2 c (512 k).
// Stripe = 64 blocks = one XCD (bid%8 == mt). B slice (32 cols x 512 k h/l)
// = 64 KB LDS, loaded once. A (bh/bl) read global->VGPR with an explicit
// 3-step-deep rotation (fully unrolled K-loop: all indices static) so ~12
// loads stay in flight across the MFMA clusters.
// ---------------------------------------------------------------------------
__global__ __launch_bounds__(256, 2)
void admm_loop(const float* __restrict__ adb, float* __restrict__ xkp,
               float* __restrict__ tbuf,
               _Float16* __restrict__ bh, _Float16* __restrict__ bl,
               const _Float16* __restrict__ Th, const _Float16* __restrict__ Tl,
               float* __restrict__ enc, _Float16* __restrict__ ench,
               _Float16* __restrict__ encl, int* __restrict__ solved,
               int* __restrict__ bar) {
    const int bid = blockIdx.x;
    const int tid = threadIdx.x, lane = tid & 63;
    const int wv = tid >> 6;

    // XCD-pinned mapping: stripe mt = bid%8; member = bid/8 in 0..63.
    const int mt = bid & 7;
    const int memb = bid >> 3;             // 0..63
    const int nt = memb >> 1;              // 0..31 (32-col tile)
    const int c  = memb & 1;               // K-half
    const int m0 = mt << 7;                // stripe base row (128 rows)
    const int n0 = nt << 5;                // tile base col (32 cols)

    __shared__ _Float16 Bs[64 * 512];      // 64 KB persistent B slice

    // ---- one-time B load: chunk = ((hl*2 + j)*16 + s), 16 chunks per wave
    #pragma unroll
    for (int i = 0; i < 16; ++i) {
        const int chunk = (wv << 4) + i;
        const int hl = chunk >> 5, ct = (chunk >> 4) & 1, s = chunk & 15;
        const _Float16* src = (hl ? Tl : Th) +
            ((((size_t)((nt << 1) + ct) * 32 + (c << 4) + s) << 9) +
             ((size_t)lane << 3));
        __builtin_amdgcn_global_load_lds(
            (const __attribute__((address_space(1))) void*)src,
            (__attribute__((address_space(3))) void*)&Bs[(size_t)chunk << 9],
            16, 0, 0);
    }
    __syncthreads();

    // per-stripe barrier slots (64 ints per stripe)
    int* slots = bar + (mt << 6);

    // update-phase: 2 rows per block (waves 0-1), covering stripe mt
    const int urow = m0 + (memb << 1) + wv;

    // wave's global row-tile base: each wave owns 32 rows (2 tiles)
    const int rt0 = (mt << 3) + (wv << 1);

    for (int it = 0; it < MAX_ITERS; ++it) {
        // ================= GEMM phase (no barriers inside) =================
        floatx4 acc[2][2] = {};
        half8 pah[3][2], pal[3][2];
        #pragma unroll
        for (int d = 0; d < 3; ++d) {
            const size_t koff = ((size_t)((c << 4) + d)) << 9;
            #pragma unroll
            for (int i = 0; i < 2; ++i) {
                const size_t aoff =
                    (((size_t)(rt0 + i)) << 14) + koff + ((size_t)lane << 3);
                pah[d][i] = *(const half8*)&bh[aoff];
                pal[d][i] = *(const half8*)&bl[aoff];
            }
        }
        #pragma unroll
        for (int s = 0; s < 16; ++s) {
            const int d = s % 3;
            half8 bhf[2], blf[2];
            #pragma unroll
            for (int j = 0; j < 2; ++j) {
                bhf[j] = *(const half8*)&Bs[(((j << 4) | s) << 9) + (lane << 3)];
                blf[j] = *(const half8*)&Bs[((((2 + j) << 4) | s) << 9) + (lane << 3)];
            }
            half8 ah0 = pah[d][0], ah1 = pah[d][1];
            half8 al0 = pal[d][0], al1 = pal[d][1];
            if (s + 3 < 16) {
                const size_t koff = ((size_t)((c << 4) + s + 3)) << 9;
                #pragma unroll
                for (int i = 0; i < 2; ++i) {
                    const size_t aoff =
                        (((size_t)(rt0 + i)) << 14) + koff + ((size_t)lane << 3);
                    pah[d][i] = *(const half8*)&bh[aoff];
                    pal[d][i] = *(const half8*)&bl[aoff];
                }
            }
            #pragma unroll
            for (int j = 0; j < 2; ++j) {
                acc[0][j] = __builtin_amdgcn_mfma_f32_16x16x32_f16(
                    ah0, blf[j], acc[0][j], 0, 0, 0);
                acc[0][j] = __builtin_amdgcn_mfma_f32_16x16x32_f16(
                    al0, bhf[j], acc[0][j], 0, 0, 0);
                acc[0][j] = __builtin_amdgcn_mfma_f32_16x16x32_f16(
                    ah0, bhf[j], acc[0][j], 0, 0, 0);
                acc[1][j] = __builtin_amdgcn_mfma_f32_16x16x32_f16(
                    ah1, blf[j], acc[1][j], 0, 0, 0);
                acc[1][j] = __builtin_amdgcn_mfma_f32_16x16x32_f16(
                    al1, bhf[j], acc[1][j], 0, 0, 0);
                acc[1][j] = __builtin_amdgcn_mfma_f32_16x16x32_f16(
                    ah1, bhf[j], acc[1][j], 0, 0, 0);
            }
        }
        // C/D: col = lane&15, row = (lane>>4)*4 + reg  [m89 verified]
        {
            float* op = xkp + (size_t)c * MM;
            const int orow = (lane >> 4) << 2;
            #pragma unroll
            for (int i = 0; i < 2; ++i) {
                const int gr = m0 + (wv << 5) + (i << 4) + orow;
                #pragma unroll
                for (int j = 0; j < 2; ++j) {
                    const int gc = n0 + (j << 4) + (lane & 15);
                    #pragma unroll
                    for (int r = 0; r < 4; ++r)
                        op[(size_t)(gr + r) * MOUT + gc] = acc[i][j][r];
                }
            }
        }
        gbar64s(slots, memb, 2 * it + 1);

        // ================= update phase =================
        if (wv < 2 && !((volatile const int*)solved)[urow]) {
            const int row = urow;
            float vn[16];
            float dx2 = 0.f, x2 = 0.f;
            #pragma unroll
            for (int cch = 0; cch < 4; ++cch) {
                const int k4 = (cch << 8) + (lane << 2);
                const size_t jj = ((size_t)row << 10) + k4;
                float4 p0 = *(const float4*)&xkp[jj];
                float4 p1 = *(const float4*)&xkp[(size_t)MM + jj];
                float4 tp = *(const float4*)&tbuf[jj];
                float4 aa = *(const float4*)&adb[jj];
                float kxa[4] = {p0.x + p1.x, p0.y + p1.y, p0.z + p1.z, p0.w + p1.w};
                float tpa[4] = {tp.x, tp.y, tp.z, tp.w};
                float aaa[4] = {aa.x, aa.y, aa.z, aa.w};
                float tna[4];
                half4 h, l;
                #pragma unroll
                for (int e = 0; e < 4; ++e) {
                    float vprev = shrinkf(tpa[e]);
                    float uu = tpa[e] - vprev;
                    float tn = kxa[e] + uu;          // = u + xk  (ref order)
                    float vv = shrinkf(tn);
                    float un = tn - vv;              // u_new = (u + xk) - v_new
                    float d = vv - vprev;
                    dx2 += d * d;
                    x2 += vv * vv;
                    vn[(cch << 2) + e] = vv;
                    tna[e] = tn;
                    float nb = (aaa[e] + vv) - un;   // (adb + v_new) - u_new
                    _Float16 hh = (_Float16)nb;
                    h[e] = hh;
                    l[e] = (_Float16)(nb - (float)hh);
                }
                *(float4*)&tbuf[jj] = make_float4(tna[0], tna[1], tna[2], tna[3]);
                size_t off = swz(row, k4);
                *(half4*)&bh[off] = h;
                *(half4*)&bl[off] = l;
            }
            #pragma unroll
            for (int off = 32; off; off >>= 1) {
                dx2 += __shfl_xor(dx2, off);
                x2  += __shfl_xor(x2, off);
            }
            if (dx2 < TOLF * TOLF * x2) {   // x2==0 -> false (NaN semantics)
                #pragma unroll
                for (int cch = 0; cch < 4; ++cch) {
                    const int k4 = (cch << 8) + (lane << 2);
                    const size_t jj = ((size_t)row << 10) + k4;
                    float va[4] = {vn[(cch << 2) + 0], vn[(cch << 2) + 1],
                                   vn[(cch << 2) + 2], vn[(cch << 2) + 3]};
                    *(float4*)&enc[jj] = make_float4(va[0], va[1], va[2], va[3]);
                    half4 h, l;
                    #pragma unroll
                    for (int e = 0; e < 4; ++e) {
                        _Float16 hh = (_Float16)va[e];
                        h[e] = hh;
                        l[e] = (_Float16)(va[e] - (float)hh);
                    }
                    size_t off = swz(row, k4);
                    *(half4*)&ench[off] = h;
                    *(half4*)&encl[off] = l;
                }
                if (lane == 0) ((volatile int*)solved)[row] = 1;
            }
        }
        gbar64s(slots, memb, 2 * it + 2);

        // stripe-local exact early exit over 128 rows (stripe-uniform)
        bool d0 = ((volatile const int*)solved)[m0 + lane] != 0;
        bool d1 = ((volatile const int*)solved)[m0 + 64 + lane] != 0;
        if ((__ballot(d0) & __ballot(d1)) == ~0ull) break;
    }
}

// ---------------------------------------------------------------------------
// Fallback (non-persistent) iteration kernels — proven baseline path.
// ---------------------------------------------------------------------------
__global__ __launch_bounds__(256, 2)
void gemm_xk(const _Float16* __restrict__ bh, const _Float16* __restrict__ bl,
             const _Float16* __restrict__ Th, const _Float16* __restrict__ Tl,
             float* __restrict__ xkp, const int* __restrict__ solved) {
    const int bid = blockIdx.x;
    const int c = bid & 1, t = bid >> 1;
    const int mt = t >> 4, nt = t & 15;
    const int m0 = mt << 6, n0 = nt << 6;
    const int tid = threadIdx.x, lane = tid & 63;

    bool done = ((volatile const int*)solved)[m0 + lane] != 0;
    if (__ballot(done) == ~0ull) return;

    __shared__ _Float16 Ash[16 * 512];

    const int wv = tid >> 6;
    const int wm = (wv >> 1) & 1, wn = wv & 1;
    const int kf0 = c << 4;

    const _Float16* sarr = (wv == 0) ? bh : (wv == 1) ? bl : (wv == 2) ? Th : Tl;
    const int stile = (wv < 2) ? (mt << 2) : (nt << 2);

    floatx4 acc[2][2] = {};
    for (int s = 0; s < 16; ++s) {
        #pragma unroll
        for (int i = 0; i < 4; ++i) {
            const _Float16* src = sarr +
                ((((size_t)(stile + i) * 32 + kf0 + s) << 9) + ((size_t)lane << 3));
            __builtin_amdgcn_global_load_lds(
                (const __attribute__((address_space(1))) void*)src,
                (__attribute__((address_space(3))) void*)
                    &Ash[(((wv << 2) + i) << 9)],
                16, 0, 0);
        }
        __syncthreads();

        half8 ah[2], al[2], bhf[2], blf[2];
        #pragma unroll
        for (int i = 0; i < 2; ++i) {
            const int at = (wm << 1) + i;
            ah[i]  = *(const half8*)&Ash[((0 << 11) + (at << 9)) + (lane << 3)];
            al[i]  = *(const half8*)&Ash[((1 << 11) + (at << 9)) + (lane << 3)];
            const int bt = (wn << 1) + i;
            bhf[i] = *(const half8*)&Ash[((2 << 11) + (bt << 9)) + (lane << 3)];
            blf[i] = *(const half8*)&Ash[((3 << 11) + (bt << 9)) + (lane << 3)];
        }
        #pragma unroll
        for (int i = 0; i < 2; ++i)
            #pragma unroll
            for (int jj = 0; jj < 2; ++jj) {
                acc[i][jj] = __builtin_amdgcn_mfma_f32_16x16x32_f16(
                    ah[i], blf[jj], acc[i][jj], 0, 0, 0);
                acc[i][jj] = __builtin_amdgcn_mfma_f32_16x16x32_f16(
                    al[i], bhf[jj], acc[i][jj], 0, 0, 0);
                acc[i][jj] = __builtin_amdgcn_mfma_f32_16x16x32_f16(
                    ah[i], bhf[jj], acc[i][jj], 0, 0, 0);
            }
        __syncthreads();
    }

    float* op = xkp + (size_t)c * MM;
    const int orow = (lane >> 4) << 2;
    #pragma unroll
    for (int i = 0; i < 2; ++i) {
        const int gr = m0 + (wm << 5) + (i << 4) + orow;
        #pragma unroll
        for (int jj = 0; jj < 2; ++jj) {
            const int gc = n0 + (wn << 5) + (jj << 4) + (lane & 15);
            #pragma unroll
            for (int r = 0; r < 4; ++r)
                op[(size_t)(gr + r) * MOUT + gc] = acc[i][jj][r];
        }
    }
}

__global__ __launch_bounds__(256) void update(const float* __restrict__ adb,
                                              const float* __restrict__ xkp,
                                              float* __restrict__ t,
                                              _Float16* __restrict__ bh,
                                              _Float16* __restrict__ bl,
                                              float* __restrict__ enc,
                                              _Float16* __restrict__ ench,
                                              _Float16* __restrict__ encl,
                                              int* solved) {
    const int tid = threadIdx.x, lane = tid & 63;
    const int row = (blockIdx.x << 2) + (tid >> 6);
    if (((volatile const int*)solved)[row]) return;

    float vn[16];
    float dx2 = 0.f, x2 = 0.f;
    #pragma unroll
    for (int cch = 0; cch < 4; ++cch) {
        const int k4 = (cch << 8) + (lane << 2);
        const size_t j = ((size_t)row << 10) + k4;
        float4 p0 = *(const float4*)&xkp[j];
        float4 p1 = *(const float4*)&xkp[(size_t)MM + j];
        float4 tp = *(const float4*)&t[j];
        float4 aa = *(const float4*)&adb[j];
        float kxa[4] = {p0.x + p1.x, p0.y + p1.y, p0.z + p1.z, p0.w + p1.w};
        float tpa[4] = {tp.x, tp.y, tp.z, tp.w};
        float aaa[4] = {aa.x, aa.y, aa.z, aa.w};
        float tna[4];
        half4 h, l;
        #pragma unroll
        for (int e = 0; e < 4; ++e) {
            float vprev = shrinkf(tpa[e]);
            float uu = tpa[e] - vprev;
            float tn = kxa[e] + uu;
            float vv = shrinkf(tn);
            float un = tn - vv;
            float d = vv - vprev;
            dx2 += d * d;
            x2 += vv * vv;
            vn[(cch << 2) + e] = vv;
            tna[e] = tn;
            float nb = (aaa[e] + vv) - un;
            _Float16 hh = (_Float16)nb;
            h[e] = hh;
            l[e] = (_Float16)(nb - (float)hh);
        }
        *(float4*)&t[j] = make_float4(tna[0], tna[1], tna[2], tna[3]);
        size_t off = swz(row, k4);
        *(half4*)&bh[off] = h;
        *(half4*)&bl[off] = l;
    }
    #pragma unroll
    for (int off = 32; off; off >>= 1) {
        dx2 += __shfl_xor(dx2, off);
        x2  += __shfl_xor(x2, off);
    }
    if (dx2 < TOLF * TOLF * x2) {
        #pragma unroll
        for (int cch = 0; cch < 4; ++cch) {
            const int k4 = (cch << 8) + (lane << 2);
            const size_t j = ((size_t)row << 10) + k4;
            float va[4] = {vn[(cch << 2) + 0], vn[(cch << 2) + 1],
                           vn[(cch << 2) + 2], vn[(cch << 2) + 3]};
            *(float4*)&enc[j] = make_float4(va[0], va[1], va[2], va[3]);
            half4 h, l;
            #pragma unroll
            for (int e = 0; e < 4; ++e) {
                _Float16 hh = (_Float16)va[e];
                h[e] = hh;
                l[e] = (_Float16)(va[e] - (float)hh);
            }
            size_t off = swz(row, k4);
            *(half4*)&ench[off] = h;
            *(half4*)&encl[off] = l;
        }
        if (lane == 0) ((volatile int*)solved)[row] = 1;
    }
}

// ---------------------------------------------------------------------------
// dec = enc @ w, split-f16 MFMA, runs ONCE. 128x128 tile, S=8 whole-partition
// A staging (64 KB), one barrier, atomicAdd epilogue (one-time cost).
// ---------------------------------------------------------------------------
__global__ __launch_bounds__(256, 2)
void mfma_dec(const _Float16* __restrict__ Ahg, const _Float16* __restrict__ Alg,
              const _Float16* __restrict__ Bhg, const _Float16* __restrict__ Blg,
              float* __restrict__ out) {
    constexpr int NSTR = NIN;              // 512
    constexpr int NT = NSTR / 128;         // 4
    const int bid = blockIdx.x;
    const int c = bid & 7, t = bid >> 3;
    const int mt = t / NT, nt = t % NT;
    const int tid = threadIdx.x, lane = tid & 63;

    __shared__ _Float16 Ash[64 * 512];     // 64 KB

    const int wv = tid >> 6;
    const int wm = (tid >> 7) & 1, wn = (tid >> 6) & 1;
    const int kf0 = c << 2;

    #pragma unroll
    for (int i = 0; i < 16; ++i) {
        const int chunk = (wv << 4) + i;
        const int rt = chunk >> 3, kc = (chunk >> 1) & 3, hl = chunk & 1;
        const _Float16* src = (hl ? Alg : Ahg) +
            ((((size_t)((mt << 3) + rt) * 32 + kf0 + kc) << 9) + ((size_t)lane << 3));
        __builtin_amdgcn_global_load_lds(
            (const __attribute__((address_space(1))) void*)src,
            (__attribute__((address_space(3))) void*)&Ash[(size_t)chunk << 9],
            16, 0, 0);
    }
    __syncthreads();

    const int ct0 = nt * 8 + (wn << 2);
    const _Float16* pBh = Bhg + ((((size_t)ct0 * 32 + kf0) * 64 + lane) << 3);
    const _Float16* pBl = Blg + ((((size_t)ct0 * 32 + kf0) * 64 + lane) << 3);

    floatx4 acc[4][4] = {};
    #pragma unroll
    for (int s = 0; s < 4; ++s) {
        half8 bhf[4], blf[4];
        #pragma unroll
        for (int j = 0; j < 4; ++j) {
            bhf[j] = *(const half8*)(pBh + ((size_t)j << 14) + ((size_t)s << 9));
            blf[j] = *(const half8*)(pBl + ((size_t)j << 14) + ((size_t)s << 9));
        }
        half8 ah[4], al[4];
        #pragma unroll
        for (int i = 0; i < 4; ++i) {
            const int rt = (wm << 2) + i;
            ah[i] = *(const half8*)&Ash[((((rt << 2) + s) << 1) << 9) + (lane << 3)];
            al[i] = *(const half8*)&Ash[(((((rt << 2) + s) << 1) + 1) << 9) + (lane << 3)];
        }
        #pragma unroll
        for (int i = 0; i < 4; ++i)
            #pragma unroll
            for (int j = 0; j < 4; ++j) {
                acc[i][j] = __builtin_amdgcn_mfma_f32_16x16x32_f16(
                    ah[i], blf[j], acc[i][j], 0, 0, 0);
                acc[i][j] = __builtin_amdgcn_mfma_f32_16x16x32_f16(
                    al[i], bhf[j], acc[i][j], 0, 0, 0);
                acc[i][j] = __builtin_amdgcn_mfma_f32_16x16x32_f16(
                    ah[i], bhf[j], acc[i][j], 0, 0, 0);
            }
    }

    const int orow = (lane >> 4) << 2;
    #pragma unroll
    for (int i = 0; i < 4; ++i) {
        const int gr = (mt << 7) + (wm << 6) + (i << 4) + orow;
        #pragma unroll
        for (int j = 0; j < 4; ++j) {
            const int gc = nt * 128 + (wn << 6) + (j << 4) + (lane & 15);
            #pragma unroll
            for (int r = 0; r < 4; ++r)
                atomicAdd(&out[(size_t)(gr + r) * NSTR + gc], acc[i][j][r]);
        }
    }
}

// ---------------------------------------------------------------------------
extern "C" void kernel_launch(void* const* d_in, const int* in_sizes, int n_in,
                              void* d_out, int out_size, void* d_ws, size_t ws_size,
                              hipStream_t stream) {
    const float* x    = (const float*)d_in[0];
    const float* w    = (const float*)d_in[1];
    const float* Minv = (const float*)d_in[2];

    float* enc = (float*)d_out;          // encoded: 1024*1024
    float* dec = enc + MM;               // decoded: 1024*512

    // ws (floats): adb MM | t MM | xkp 2*MM | halves: bh,bl,Th,Tl,ench,encl MM,
    // wsh,wsl MM/2 | solved[1024] + barrier slots. ~30 MB. (unchanged layout)
    float* ws  = (float*)d_ws;
    float* adb = ws;
    float* t   = ws + (size_t)MM;
    float* xkp = ws + 2 * (size_t)MM;

    _Float16* bh   = (_Float16*)(ws + 4 * (size_t)MM);
    _Float16* bl   = bh + (size_t)MM;
    _Float16* Th   = bl + (size_t)MM;
    _Float16* Tl   = Th + (size_t)MM;
    _Float16* ench = Tl + (size_t)MM;
    _Float16* encl = ench + (size_t)MM;
    _Float16* wsh  = encl + (size_t)MM;
    _Float16* wsl  = wsh + (size_t)(NIN * MOUT);
    int* solved    = (int*)(wsl + (size_t)(NIN * MOUT));
    int* bar       = solved + 1088;      // 8 stripes x 64 slot ints

    zero_init<<<(MM + 255) / 256, 256, 0, stream>>>(t, enc, dec, (float*)ench,
                                                    (float*)encl, solved);
    split_minv<<<512, 256, 0, stream>>>(Minv, Th, Tl);
    split_w<<<256, 256, 0, stream>>>(w, wsh, wsl);
    gemm_adb<<<256, 256, 0, stream>>>(x, w, adb, bh, bl);

    void* cargs[] = {(void*)&adb, (void*)&xkp, (void*)&t,
                     (void*)&bh,  (void*)&bl,  (void*)&Th, (void*)&Tl,
                     (void*)&enc, (void*)&ench, (void*)&encl, (void*)&solved,
                     (void*)&bar};
    // Cooperative launch used ONLY as a co-residency guarantee (deadlock
    // safety for the spin barriers); no grid.sync() is ever called.
    hipError_t e = hipLaunchCooperativeKernel(
        reinterpret_cast<void*>(admm_loop), dim3(512), dim3(256), cargs, 0, stream);
    if (e != hipSuccess) {
        // fallback: classic 2-kernel iteration loop
        for (int it = 0; it < MAX_ITERS; ++it) {
            gemm_xk<<<512, 256, 0, stream>>>(bh, bl, Th, Tl, xkp, solved);
            update<<<256, 256, 0, stream>>>(adb, xkp, t, bh, bl, enc, ench, encl,
                                            solved);
        }
    }

    mfma_dec<<<256, 256, 0, stream>>>(ench, encl, wsh, wsl, dec);
}

// Round 6
// 1356.869 us; speedup vs baseline: 1.7635x; 1.7635x over previous
//
#include <hip/hip_runtime.h>

typedef _Float16 half8 __attribute__((ext_vector_type(8)));
typedef _Float16 half4 __attribute__((ext_vector_type(4)));
typedef float floatx4 __attribute__((ext_vector_type(4)));

static constexpr int BATCH = 1024;
static constexpr int NIN   = 512;    // in_features
static constexpr int MOUT  = 1024;   // out_features
static constexpr float LAMBD = 0.2f;
static constexpr float TOLF  = 1e-4f;
static constexpr int MAX_ITERS = 100;
static constexpr int MM = BATCH * MOUT;   // 1M elements

// Fragment-swizzled layout for 16x16x32 MFMA operands (A: rows, B: cols), f16:
//   flat = ((tile16*32 + kchunk32)*64 + lane)*8 + elem
//   lane = (idx&15) | (((k>>3)&3)<<4), elem = k&7
__device__ __forceinline__ size_t swz(int idx, int k) {
    return ((((size_t)(idx >> 4) * 32 + (k >> 5)) * 64 +
             ((idx & 15) | (((k >> 3) & 3) << 4))) << 3) + (k & 7);
}

__device__ __forceinline__ float shrinkf(float t) {
    float a = fabsf(t) - LAMBD;
    return a > 0.f ? copysignf(a, t) : 0.f;
}

// ---------------------------------------------------------------------------
// XCD-local 32-block barrier (round-3/4 proven RMW form, monotonic seq).
// Stripe = one XCD (bid%8 pinning, HW-validated rounds 3-5): stores are
// L2-visible after the vmcnt drain in __syncthreads (write-through L1);
// arrive via one device-scope RMW; spin on gen; then L1-only invalidate.
// ---------------------------------------------------------------------------
__device__ __forceinline__ void gbar32(int* cnt, int* gen, int seq) {
    __syncthreads();                       // drains vmcnt: stores at L2
    if (threadIdx.x == 0) {
        int old = atomicAdd(cnt, 1);       // device-scope RMW, L1-bypassing
        if (old == seq * 32 - 1) {
            __hip_atomic_store(gen, seq, __ATOMIC_RELAXED,
                               __HIP_MEMORY_SCOPE_AGENT);
        } else {
            while (__hip_atomic_load(gen, __ATOMIC_RELAXED,
                                     __HIP_MEMORY_SCOPE_AGENT) < seq)
                __builtin_amdgcn_s_sleep(1);
        }
    }
    __syncthreads();
    asm volatile("buffer_inv sc0" ::: "memory");   // L1-only invalidate
}

// ---------------------------------------------------------------------------
// zero-init: t (fallback), enc, dec, swizzled enc halves, solved + barriers
// ---------------------------------------------------------------------------
__global__ __launch_bounds__(256) void zero_init(float* t, float* enc,
                                                 float* dec, float* ench_f,
                                                 float* encl_f, int* solved) {
    int i = blockIdx.x * 256 + threadIdx.x;
    if (i < MM) { t[i] = 0.f; enc[i] = 0.f; }
    if (i < MM / 2) { dec[i] = 0.f; ench_f[i] = 0.f; encl_f[i] = 0.f; }
    if (i < 4096) solved[i] = 0;   // solved[0..1023] + barrier words @ +1088
}

// ---------------------------------------------------------------------------
// Th/Tl = fragment-swizzled split-f16 of Minv (idx=n in 1024, k in 1024).
// ---------------------------------------------------------------------------
__global__ __launch_bounds__(256) void split_minv(const float* __restrict__ Minv,
                                                  _Float16* __restrict__ Th,
                                                  _Float16* __restrict__ Tl) {
    int g = blockIdx.x * 256 + threadIdx.x;   // 131072 threads
    int n = g & 1023, k0 = (g >> 10) << 3;
    half8 h, l;
    #pragma unroll
    for (int e = 0; e < 8; ++e) {
        float val = Minv[(size_t)(k0 + e) * MOUT + n];
        _Float16 hh = (_Float16)val;
        h[e] = hh;
        l[e] = (_Float16)(val - (float)hh);
    }
    size_t off = swz(n, k0);
    *(half8*)&Th[off] = h;
    *(half8*)&Tl[off] = l;
}

// ---------------------------------------------------------------------------
// wsh/wsl = fragment-swizzled split-f16 of weight (idx=n in 512, k in 1024).
// ---------------------------------------------------------------------------
__global__ __launch_bounds__(256) void split_w(const float* __restrict__ w,
                                               _Float16* __restrict__ wsh,
                                               _Float16* __restrict__ wsl) {
    int g = blockIdx.x * 256 + threadIdx.x;   // 65536 threads
    int n = g & 511, k0 = (g >> 9) << 3;
    half8 h, l;
    #pragma unroll
    for (int e = 0; e < 8; ++e) {
        float val = w[(size_t)(k0 + e) * NIN + n];
        _Float16 hh = (_Float16)val;
        h[e] = hh;
        l[e] = (_Float16)(val - (float)hh);
    }
    size_t off = swz(n, k0);
    *(half8*)&wsh[off] = h;
    *(half8*)&wsl[off] = l;
}

// ---------------------------------------------------------------------------
// adb = x @ w^T (fp32, once). Epilogue emits beff = adb as A-swizzled h/l.
// ---------------------------------------------------------------------------
__global__ __launch_bounds__(256) void gemm_adb(const float* __restrict__ x,
                                                const float* __restrict__ w,
                                                float* __restrict__ adb,
                                                _Float16* __restrict__ bh,
                                                _Float16* __restrict__ bl) {
    __shared__ float As[16][68];
    __shared__ float Bs[16][68];
    const int tid = threadIdx.x;
    const int i0 = (blockIdx.x >> 4) * 64, j0 = (blockIdx.x & 15) * 64;
    const int tx = tid & 15, ty = tid >> 4;
    const int lr = tid >> 2, lk = (tid & 3) << 2;
    float acc[4][4] = {};
    for (int k0 = 0; k0 < NIN; k0 += 16) {
        float4 a4 = *(const float4*)&x[(i0 + lr) * NIN + k0 + lk];
        As[lk + 0][lr] = a4.x; As[lk + 1][lr] = a4.y;
        As[lk + 2][lr] = a4.z; As[lk + 3][lr] = a4.w;
        float4 b4 = *(const float4*)&w[(j0 + lr) * NIN + k0 + lk];
        Bs[lk + 0][lr] = b4.x; Bs[lk + 1][lr] = b4.y;
        Bs[lk + 2][lr] = b4.z; Bs[lk + 3][lr] = b4.w;
        __syncthreads();
        #pragma unroll
        for (int kk = 0; kk < 16; ++kk) {
            float4 a_ = *(const float4*)&As[kk][ty << 2];
            float4 b_ = *(const float4*)&Bs[kk][tx << 2];
            #pragma unroll
            for (int r = 0; r < 4; ++r) {
                float av = r == 0 ? a_.x : r == 1 ? a_.y : r == 2 ? a_.z : a_.w;
                acc[r][0] = fmaf(av, b_.x, acc[r][0]);
                acc[r][1] = fmaf(av, b_.y, acc[r][1]);
                acc[r][2] = fmaf(av, b_.z, acc[r][2]);
                acc[r][3] = fmaf(av, b_.w, acc[r][3]);
            }
        }
        __syncthreads();
    }
    const int k4 = j0 + (tx << 2);
    #pragma unroll
    for (int r = 0; r < 4; ++r) {
        const int row = i0 + (ty << 2) + r;
        *(float4*)&adb[(size_t)row * MOUT + k4] =
            make_float4(acc[r][0], acc[r][1], acc[r][2], acc[r][3]);
        half4 h, l;
        #pragma unroll
        for (int e = 0; e < 4; ++e) {
            _Float16 hh = (_Float16)acc[r][e];
            h[e] = hh;
            l[e] = (_Float16)(acc[r][e] - (float)hh);
        }
        size_t off = swz(row, k4);
        *(half4*)&bh[off] = h;
        *(half4*)&bl[off] = l;
    }
}

// ---------------------------------------------------------------------------
// FUSED persistent ADMM loop v3: full-K gemm + register-resident t/adb.
// 256 blocks x 512 threads (1/CU, 8 waves): 8 stripes (mt, 128 rows) x 32 nt
// (32 n-cols each). Block's Minv slice (32 n x 1024 k, h/l) = 128 KB LDS,
// loaded once. MFMA computes D = Minv_frag x beff_frag (operands swapped ->
// output transposed: lane holds 1 batch row x 8 n-cols), with TWO accumulator
// sets (k-chunks 0..15 / 16..31) so xk = p0 + p1 bit-matches the verified
// split-K pipeline. Update fuses into the epilogue: t and adb live in
// registers for all 100 iterations; only beff h/l + 2-float/row norm partials
// are stored. Phase B: deterministic tree-sum of 32 partials, freeze rows.
// enc flushed once at the end from frozen t regs (enc = shrink(t_freeze)).
// ---------------------------------------------------------------------------
__global__ __launch_bounds__(512, 1)
void admm_loop(const float* __restrict__ adb, float* __restrict__ part,
               _Float16* __restrict__ bh, _Float16* __restrict__ bl,
               const _Float16* __restrict__ Th, const _Float16* __restrict__ Tl,
               float* __restrict__ enc, _Float16* __restrict__ ench,
               _Float16* __restrict__ encl, int* __restrict__ solved,
               int* __restrict__ bar) {
    const int bid = blockIdx.x;
    const int tid = threadIdx.x, lane = tid & 63;
    const int w = tid >> 6;                // wave 0..7
    const int g = lane >> 4;               // 0..3 (n-subgroup)
    const int bcol = lane & 15;            // batch sub-row
    const int mt = bid & 7;                // stripe = XCD
    const int nt = bid >> 3;               // 0..31: 32-col n-tile pair
    const int n0 = nt << 5;
    const int m0 = mt << 7;                // stripe base batch row (128 rows)
    const int brow = m0 + (w << 4) + bcol; // lane's (only) batch row
    const int btile = (mt << 3) + w;       // beff fragment row-tile

    __shared__ _Float16 Bs[128 * 512];     // 128 KB persistent Minv slice
    __shared__ int s_exit;

    // ---- one-time Minv load: chunk = ((i*2+hl)*32 + s); wave w: 16 chunks
    #pragma unroll
    for (int q = 0; q < 16; ++q) {
        const int chunk = (w << 4) + q;
        const int i = chunk >> 6, hl = (chunk >> 5) & 1, s = chunk & 31;
        const _Float16* src = (hl ? Tl : Th) +
            ((((size_t)((nt << 1) + i) * 32 + s) << 9) + ((size_t)lane << 3));
        __builtin_amdgcn_global_load_lds(
            (const __attribute__((address_space(1))) void*)src,
            (__attribute__((address_space(3))) void*)&Bs[(size_t)chunk << 9],
            16, 0, 0);
    }
    __syncthreads();

    // per-stripe barrier words (128 B apart)
    int* gcnt = bar + (mt << 5);
    int* ggen = bar + (mt << 5) + 16;

    // register-resident state: 8 elements/lane = (2 n-tiles) x (4 n each)
    float treg[8] = {};
    float adbreg[8];
    #pragma unroll
    for (int i = 0; i < 2; ++i) {
        float4 a4 = *(const float4*)
            &adb[(size_t)brow * MOUT + n0 + (i << 4) + (g << 2)];
        adbreg[(i << 2) + 0] = a4.x; adbreg[(i << 2) + 1] = a4.y;
        adbreg[(i << 2) + 2] = a4.z; adbreg[(i << 2) + 3] = a4.w;
    }
    bool sflag = false;

#define KSTEP(ACC, S)                                                          \
    {                                                                          \
        const size_t boff =                                                    \
            (((size_t)(btile * 32 + (S))) << 9) + ((size_t)lane << 3);         \
        const half8 bhf = *(const half8*)&bh[boff];                            \
        const half8 blf = *(const half8*)&bl[boff];                            \
        _Pragma("unroll")                                                      \
        for (int i_ = 0; i_ < 2; ++i_) {                                       \
            const half8 ahf = *(const half8*)                                  \
                &Bs[((size_t)((i_ << 6) + (S)) << 9) + (lane << 3)];           \
            const half8 alf = *(const half8*)                                  \
                &Bs[((size_t)((i_ << 6) + 32 + (S)) << 9) + (lane << 3)];      \
            ACC[i_] = __builtin_amdgcn_mfma_f32_16x16x32_f16(                  \
                alf, bhf, ACC[i_], 0, 0, 0);                                   \
            ACC[i_] = __builtin_amdgcn_mfma_f32_16x16x32_f16(                  \
                ahf, blf, ACC[i_], 0, 0, 0);                                   \
            ACC[i_] = __builtin_amdgcn_mfma_f32_16x16x32_f16(                  \
                ahf, bhf, ACC[i_], 0, 0, 0);                                   \
        }                                                                      \
    }

    for (int it = 0; it < MAX_ITERS; ++it) {
        // ============ PHASE A: full-K gemm + fused elementwise update ======
        floatx4 a0[2] = {}, a1[2] = {};
        #pragma unroll 4
        for (int s = 0; s < 16; ++s) KSTEP(a0, s)
        #pragma unroll 4
        for (int s = 16; s < 32; ++s) KSTEP(a1, s)

        float dx2 = 0.f, x2 = 0.f;
        if (!sflag) {
            #pragma unroll
            for (int i = 0; i < 2; ++i) {
                half4 h, l;
                #pragma unroll
                for (int r = 0; r < 4; ++r) {
                    float xk = a0[i][r] + a1[i][r];   // p0 + p1 (ref order)
                    float t_ = treg[(i << 2) + r];
                    float vprev = shrinkf(t_);
                    float uu = t_ - vprev;
                    float tn = xk + uu;               // = u + xk
                    float vv = shrinkf(tn);
                    float un = tn - vv;               // u_new
                    float d = vv - vprev;
                    dx2 += d * d;
                    x2 += vv * vv;
                    treg[(i << 2) + r] = tn;
                    float nb = (adbreg[(i << 2) + r] + vv) - un;
                    _Float16 hh = (_Float16)nb;
                    h[r] = hh;
                    l[r] = (_Float16)(nb - (float)hh);
                }
                size_t off = swz(brow, n0 + (i << 4) + (g << 2));
                *(half4*)&bh[off] = h;
                *(half4*)&bl[off] = l;
            }
        }
        // per-row partial over this block's 32 n (reduce across g: lanes
        // ^16,^32 share the same batch row -> uniform shuffle groups)
        dx2 += __shfl_xor(dx2, 16); dx2 += __shfl_xor(dx2, 32);
        x2  += __shfl_xor(x2, 16);  x2  += __shfl_xor(x2, 32);
        if (g == 0 && !sflag)
            *(float2*)&part[(((size_t)brow << 5) | nt) << 1] =
                make_float2(dx2, x2);

        gbar32(gcnt, ggen, 2 * it + 1);

        // ============ PHASE B: norm finish + freeze (4 rows/block) =========
        if (w < 4) {
            const int urow = m0 + ((bid >> 3) << 2) + w;
            if (!((volatile const int*)solved)[urow]) {
                float2 p = *(const float2*)
                    &part[(((size_t)urow << 5) | (lane & 31)) << 1];
                float rdx = p.x, rx = p.y;
                #pragma unroll
                for (int off = 16; off; off >>= 1) {
                    rdx += __shfl_xor(rdx, off);
                    rx  += __shfl_xor(rx, off);
                }
                if (rdx < TOLF * TOLF * rx) {   // x2==0 -> false (NaN sem.)
                    if (lane == 0) ((volatile int*)solved)[urow] = 1;
                }
            }
        }
        gbar32(gcnt, ggen, 2 * it + 2);

        // refresh frozen mask + stripe-uniform exact early exit
        sflag = ((volatile const int*)solved)[brow] != 0;
        if (tid == 0) s_exit = 0;
        __syncthreads();
        if (!sflag && g == 0) s_exit = 1;   // benign same-value race
        __syncthreads();
        if (s_exit == 0) break;
    }
#undef KSTEP

    // ============ final flush: enc = shrink(t_frozen) for solved rows ======
    if (sflag) {
        #pragma unroll
        for (int i = 0; i < 2; ++i) {
            float va[4]; half4 h, l;
            #pragma unroll
            for (int r = 0; r < 4; ++r) {
                float vv = shrinkf(treg[(i << 2) + r]);
                va[r] = vv;
                _Float16 hh = (_Float16)vv;
                h[r] = hh;
                l[r] = (_Float16)(vv - (float)hh);
            }
            *(float4*)&enc[(size_t)brow * MOUT + n0 + (i << 4) + (g << 2)] =
                make_float4(va[0], va[1], va[2], va[3]);
            size_t off = swz(brow, n0 + (i << 4) + (g << 2));
            *(half4*)&ench[off] = h;
            *(half4*)&encl[off] = l;
        }
    }
}

// ---------------------------------------------------------------------------
// Fallback (non-persistent) iteration kernels — proven baseline path.
// ---------------------------------------------------------------------------
__global__ __launch_bounds__(256, 2)
void gemm_xk(const _Float16* __restrict__ bh, const _Float16* __restrict__ bl,
             const _Float16* __restrict__ Th, const _Float16* __restrict__ Tl,
             float* __restrict__ xkp, const int* __restrict__ solved) {
    const int bid = blockIdx.x;
    const int c = bid & 1, t = bid >> 1;
    const int mt = t >> 4, nt = t & 15;
    const int m0 = mt << 6, n0 = nt << 6;
    const int tid = threadIdx.x, lane = tid & 63;

    bool done = ((volatile const int*)solved)[m0 + lane] != 0;
    if (__ballot(done) == ~0ull) return;

    __shared__ _Float16 Ash[16 * 512];

    const int wv = tid >> 6;
    const int wm = (wv >> 1) & 1, wn = wv & 1;
    const int kf0 = c << 4;

    const _Float16* sarr = (wv == 0) ? bh : (wv == 1) ? bl : (wv == 2) ? Th : Tl;
    const int stile = (wv < 2) ? (mt << 2) : (nt << 2);

    floatx4 acc[2][2] = {};
    for (int s = 0; s < 16; ++s) {
        #pragma unroll
        for (int i = 0; i < 4; ++i) {
            const _Float16* src = sarr +
                ((((size_t)(stile + i) * 32 + kf0 + s) << 9) + ((size_t)lane << 3));
            __builtin_amdgcn_global_load_lds(
                (const __attribute__((address_space(1))) void*)src,
                (__attribute__((address_space(3))) void*)
                    &Ash[(((wv << 2) + i) << 9)],
                16, 0, 0);
        }
        __syncthreads();

        half8 ah[2], al[2], bhf[2], blf[2];
        #pragma unroll
        for (int i = 0; i < 2; ++i) {
            const int at = (wm << 1) + i;
            ah[i]  = *(const half8*)&Ash[((0 << 11) + (at << 9)) + (lane << 3)];
            al[i]  = *(const half8*)&Ash[((1 << 11) + (at << 9)) + (lane << 3)];
            const int bt = (wn << 1) + i;
            bhf[i] = *(const half8*)&Ash[((2 << 11) + (bt << 9)) + (lane << 3)];
            blf[i] = *(const half8*)&Ash[((3 << 11) + (bt << 9)) + (lane << 3)];
        }
        #pragma unroll
        for (int i = 0; i < 2; ++i)
            #pragma unroll
            for (int jj = 0; jj < 2; ++jj) {
                acc[i][jj] = __builtin_amdgcn_mfma_f32_16x16x32_f16(
                    ah[i], blf[jj], acc[i][jj], 0, 0, 0);
                acc[i][jj] = __builtin_amdgcn_mfma_f32_16x16x32_f16(
                    al[i], bhf[jj], acc[i][jj], 0, 0, 0);
                acc[i][jj] = __builtin_amdgcn_mfma_f32_16x16x32_f16(
                    ah[i], bhf[jj], acc[i][jj], 0, 0, 0);
            }
        __syncthreads();
    }

    float* op = xkp + (size_t)c * MM;
    const int orow = (lane >> 4) << 2;
    #pragma unroll
    for (int i = 0; i < 2; ++i) {
        const int gr = m0 + (wm << 5) + (i << 4) + orow;
        #pragma unroll
        for (int jj = 0; jj < 2; ++jj) {
            const int gc = n0 + (wn << 5) + (jj << 4) + (lane & 15);
            #pragma unroll
            for (int r = 0; r < 4; ++r)
                op[(size_t)(gr + r) * MOUT + gc] = acc[i][jj][r];
        }
    }
}

__global__ __launch_bounds__(256) void update(const float* __restrict__ adb,
                                              const float* __restrict__ xkp,
                                              float* __restrict__ t,
                                              _Float16* __restrict__ bh,
                                              _Float16* __restrict__ bl,
                                              float* __restrict__ enc,
                                              _Float16* __restrict__ ench,
                                              _Float16* __restrict__ encl,
                                              int* solved) {
    const int tid = threadIdx.x, lane = tid & 63;
    const int row = (blockIdx.x << 2) + (tid >> 6);
    if (((volatile const int*)solved)[row]) return;

    float vn[16];
    float dx2 = 0.f, x2 = 0.f;
    #pragma unroll
    for (int cch = 0; cch < 4; ++cch) {
        const int k4 = (cch << 8) + (lane << 2);
        const size_t j = ((size_t)row << 10) + k4;
        float4 p0 = *(const float4*)&xkp[j];
        float4 p1 = *(const float4*)&xkp[(size_t)MM + j];
        float4 tp = *(const float4*)&t[j];
        float4 aa = *(const float4*)&adb[j];
        float kxa[4] = {p0.x + p1.x, p0.y + p1.y, p0.z + p1.z, p0.w + p1.w};
        float tpa[4] = {tp.x, tp.y, tp.z, tp.w};
        float aaa[4] = {aa.x, aa.y, aa.z, aa.w};
        float tna[4];
        half4 h, l;
        #pragma unroll
        for (int e = 0; e < 4; ++e) {
            float vprev = shrinkf(tpa[e]);
            float uu = tpa[e] - vprev;
            float tn = kxa[e] + uu;
            float vv = shrinkf(tn);
            float un = tn - vv;
            float d = vv - vprev;
            dx2 += d * d;
            x2 += vv * vv;
            vn[(cch << 2) + e] = vv;
            tna[e] = tn;
            float nb = (aaa[e] + vv) - un;
            _Float16 hh = (_Float16)nb;
            h[e] = hh;
            l[e] = (_Float16)(nb - (float)hh);
        }
        *(float4*)&t[j] = make_float4(tna[0], tna[1], tna[2], tna[3]);
        size_t off = swz(row, k4);
        *(half4*)&bh[off] = h;
        *(half4*)&bl[off] = l;
    }
    #pragma unroll
    for (int off = 32; off; off >>= 1) {
        dx2 += __shfl_xor(dx2, off);
        x2  += __shfl_xor(x2, off);
    }
    if (dx2 < TOLF * TOLF * x2) {
        #pragma unroll
        for (int cch = 0; cch < 4; ++cch) {
            const int k4 = (cch << 8) + (lane << 2);
            const size_t j = ((size_t)row << 10) + k4;
            float va[4] = {vn[(cch << 2) + 0], vn[(cch << 2) + 1],
                           vn[(cch << 2) + 2], vn[(cch << 2) + 3]};
            *(float4*)&enc[j] = make_float4(va[0], va[1], va[2], va[3]);
            half4 h, l;
            #pragma unroll
            for (int e = 0; e < 4; ++e) {
                _Float16 hh = (_Float16)va[e];
                h[e] = hh;
                l[e] = (_Float16)(va[e] - (float)hh);
            }
            size_t off = swz(row, k4);
            *(half4*)&ench[off] = h;
            *(half4*)&encl[off] = l;
        }
        if (lane == 0) ((volatile int*)solved)[row] = 1;
    }
}

// ---------------------------------------------------------------------------
// dec = enc @ w, split-f16 MFMA, runs ONCE. 128x128 tile, S=8 whole-partition
// A staging (64 KB), one barrier, atomicAdd epilogue (one-time cost).
// ---------------------------------------------------------------------------
__global__ __launch_bounds__(256, 2)
void mfma_dec(const _Float16* __restrict__ Ahg, const _Float16* __restrict__ Alg,
              const _Float16* __restrict__ Bhg, const _Float16* __restrict__ Blg,
              float* __restrict__ out) {
    constexpr int NSTR = NIN;              // 512
    constexpr int NT = NSTR / 128;         // 4
    const int bid = blockIdx.x;
    const int c = bid & 7, t = bid >> 3;
    const int mt = t / NT, nt = t % NT;
    const int tid = threadIdx.x, lane = tid & 63;

    __shared__ _Float16 Ash[64 * 512];     // 64 KB

    const int wv = tid >> 6;
    const int wm = (tid >> 7) & 1, wn = (tid >> 6) & 1;
    const int kf0 = c << 2;

    #pragma unroll
    for (int i = 0; i < 16; ++i) {
        const int chunk = (wv << 4) + i;
        const int rt = chunk >> 3, kc = (chunk >> 1) & 3, hl = chunk & 1;
        const _Float16* src = (hl ? Alg : Ahg) +
            ((((size_t)((mt << 3) + rt) * 32 + kf0 + kc) << 9) + ((size_t)lane << 3));
        __builtin_amdgcn_global_load_lds(
            (const __attribute__((address_space(1))) void*)src,
            (__attribute__((address_space(3))) void*)&Ash[(size_t)chunk << 9],
            16, 0, 0);
    }
    __syncthreads();

    const int ct0 = nt * 8 + (wn << 2);
    const _Float16* pBh = Bhg + ((((size_t)ct0 * 32 + kf0) * 64 + lane) << 3);
    const _Float16* pBl = Blg + ((((size_t)ct0 * 32 + kf0) * 64 + lane) << 3);

    floatx4 acc[4][4] = {};
    #pragma unroll
    for (int s = 0; s < 4; ++s) {
        half8 bhf[4], blf[4];
        #pragma unroll
        for (int j = 0; j < 4; ++j) {
            bhf[j] = *(const half8*)(pBh + ((size_t)j << 14) + ((size_t)s << 9));
            blf[j] = *(const half8*)(pBl + ((size_t)j << 14) + ((size_t)s << 9));
        }
        half8 ah[4], al[4];
        #pragma unroll
        for (int i = 0; i < 4; ++i) {
            const int rt = (wm << 2) + i;
            ah[i] = *(const half8*)&Ash[((((rt << 2) + s) << 1) << 9) + (lane << 3)];
            al[i] = *(const half8*)&Ash[(((((rt << 2) + s) << 1) + 1) << 9) + (lane << 3)];
        }
        #pragma unroll
        for (int i = 0; i < 4; ++i)
            #pragma unroll
            for (int j = 0; j < 4; ++j) {
                acc[i][j] = __builtin_amdgcn_mfma_f32_16x16x32_f16(
                    ah[i], blf[j], acc[i][j], 0, 0, 0);
                acc[i][j] = __builtin_amdgcn_mfma_f32_16x16x32_f16(
                    al[i], bhf[j], acc[i][j], 0, 0, 0);
                acc[i][j] = __builtin_amdgcn_mfma_f32_16x16x32_f16(
                    ah[i], bhf[j], acc[i][j], 0, 0, 0);
            }
    }

    const int orow = (lane >> 4) << 2;
    #pragma unroll
    for (int i = 0; i < 4; ++i) {
        const int gr = (mt << 7) + (wm << 6) + (i << 4) + orow;
        #pragma unroll
        for (int j = 0; j < 4; ++j) {
            const int gc = nt * 128 + (wn << 6) + (j << 4) + (lane & 15);
            #pragma unroll
            for (int r = 0; r < 4; ++r)
                atomicAdd(&out[(size_t)(gr + r) * NSTR + gc], acc[i][j][r]);
        }
    }
}

// ---------------------------------------------------------------------------
extern "C" void kernel_launch(void* const* d_in, const int* in_sizes, int n_in,
                              void* d_out, int out_size, void* d_ws, size_t ws_size,
                              hipStream_t stream) {
    const float* x    = (const float*)d_in[0];
    const float* w    = (const float*)d_in[1];
    const float* Minv = (const float*)d_in[2];

    float* enc = (float*)d_out;          // encoded: 1024*1024
    float* dec = enc + MM;               // decoded: 1024*512

    // ws (floats): adb MM | t MM (fallback) | xkp/part 2*MM | halves:
    // bh,bl,Th,Tl,ench,encl MM, wsh,wsl MM/2 | solved[1024] + barriers. ~30MB.
    float* ws  = (float*)d_ws;
    float* adb = ws;
    float* t   = ws + (size_t)MM;
    float* xkp = ws + 2 * (size_t)MM;    // persistent path: norm partials

    _Float16* bh   = (_Float16*)(ws + 4 * (size_t)MM);
    _Float16* bl   = bh + (size_t)MM;
    _Float16* Th   = bl + (size_t)MM;
    _Float16* Tl   = Th + (size_t)MM;
    _Float16* ench = Tl + (size_t)MM;
    _Float16* encl = ench + (size_t)MM;
    _Float16* wsh  = encl + (size_t)MM;
    _Float16* wsl  = wsh + (size_t)(NIN * MOUT);
    int* solved    = (int*)(wsl + (size_t)(NIN * MOUT));
    int* bar       = solved + 1088;      // 8 stripes x 32 ints (128 B) apart

    zero_init<<<(MM + 255) / 256, 256, 0, stream>>>(t, enc, dec, (float*)ench,
                                                    (float*)encl, solved);
    split_minv<<<512, 256, 0, stream>>>(Minv, Th, Tl);
    split_w<<<256, 256, 0, stream>>>(w, wsh, wsl);
    gemm_adb<<<256, 256, 0, stream>>>(x, w, adb, bh, bl);

    void* cargs[] = {(void*)&adb, (void*)&xkp,
                     (void*)&bh,  (void*)&bl,  (void*)&Th, (void*)&Tl,
                     (void*)&enc, (void*)&ench, (void*)&encl, (void*)&solved,
                     (void*)&bar};
    // Cooperative launch used ONLY as a co-residency guarantee (deadlock
    // safety for the spin barriers); no grid.sync() is ever called.
    hipError_t e = hipLaunchCooperativeKernel(
        reinterpret_cast<void*>(admm_loop), dim3(256), dim3(512), cargs, 0, stream);
    if (e != hipSuccess) {
        // fallback: classic 2-kernel iteration loop
        for (int it = 0; it < MAX_ITERS; ++it) {
            gemm_xk<<<512, 256, 0, stream>>>(bh, bl, Th, Tl, xkp, solved);
            update<<<256, 256, 0, stream>>>(adb, xkp, t, bh, bl, enc, ench, encl,
                                            solved);
        }
    }

    mfma_dec<<<256, 256, 0, stream>>>(ench, encl, wsh, wsl, dec);
}

// Round 7
// 1289.068 us; speedup vs baseline: 1.8562x; 1.0526x over previous
//
#include <hip/hip_runtime.h>

typedef _Float16 half8 __attribute__((ext_vector_type(8)));
typedef _Float16 half4 __attribute__((ext_vector_type(4)));
typedef float floatx4 __attribute__((ext_vector_type(4)));
typedef float floatx16 __attribute__((ext_vector_type(16)));

static constexpr int BATCH = 1024;
static constexpr int NIN   = 512;    // in_features
static constexpr int MOUT  = 1024;   // out_features
static constexpr float LAMBD = 0.2f;
static constexpr float TOLF  = 1e-4f;
static constexpr int MAX_ITERS = 100;
static constexpr int MM = BATCH * MOUT;   // 1M elements

// 16x16x32 fragment swizzle (used by dec path): lane=(idx&15)|(((k>>3)&3)<<4)
__device__ __forceinline__ size_t swz(int idx, int k) {
    return ((((size_t)(idx >> 4) * 32 + (k >> 5)) * 64 +
             ((idx & 15) | (((k >> 3) & 3) << 4))) << 3) + (k & 7);
}

// 32x32x16 fragment swizzle (iteration GEMM): 64-lane chunk per (tile32, kc16),
// lane = (idx&31) | (((k>>3)&1)<<5), elem = k&7  [analog of verified 16x16 map]
__device__ __forceinline__ size_t swz32(int idx, int k) {
    return ((((size_t)(idx >> 5) * 64 + (k >> 4)) * 64 +
             ((idx & 31) | (((k >> 3) & 1) << 5))) << 3) + (k & 7);
}

__device__ __forceinline__ float shrinkf(float t) {
    float a = fabsf(t) - LAMBD;
    return a > 0.f ? copysignf(a, t) : 0.f;
}

// ---------------------------------------------------------------------------
// XCD-local 32-block barrier (rounds 3-6 proven). Stripe = one XCD (bid%8):
// stores L2-visible after vmcnt drain (write-through L1); one device-scope
// RMW arrive; relaxed spin; L1-only invalidate. No L2 maintenance.
// ---------------------------------------------------------------------------
__device__ __forceinline__ void gbar32(int* cnt, int* gen, int seq) {
    __syncthreads();
    if (threadIdx.x == 0) {
        int old = atomicAdd(cnt, 1);
        if (old == seq * 32 - 1) {
            __hip_atomic_store(gen, seq, __ATOMIC_RELAXED,
                               __HIP_MEMORY_SCOPE_AGENT);
        } else {
            while (__hip_atomic_load(gen, __ATOMIC_RELAXED,
                                     __HIP_MEMORY_SCOPE_AGENT) < seq)
                __builtin_amdgcn_s_sleep(1);
        }
    }
    __syncthreads();
    asm volatile("buffer_inv sc0" ::: "memory");
}

// ---------------------------------------------------------------------------
__global__ __launch_bounds__(256) void zero_init(float* t, float* enc,
                                                 float* dec, float* ench_f,
                                                 float* encl_f, int* solved) {
    int i = blockIdx.x * 256 + threadIdx.x;
    if (i < MM) { t[i] = 0.f; enc[i] = 0.f; }
    if (i < MM / 2) { dec[i] = 0.f; ench_f[i] = 0.f; encl_f[i] = 0.f; }
    if (i < 4096) solved[i] = 0;   // solved[0..1023] + barrier words @ +1088
}

// ---------------------------------------------------------------------------
// Th/Tl = 32x32-fragment-swizzled split-f16 of Minv (idx=n, k over 1024).
// A[n][k] = M_inv[k][n] so that xk[n] = sum_k A[n][k] * beff[k].
// ---------------------------------------------------------------------------
__global__ __launch_bounds__(256) void split_minv(const float* __restrict__ Minv,
                                                  _Float16* __restrict__ Th,
                                                  _Float16* __restrict__ Tl) {
    int g = blockIdx.x * 256 + threadIdx.x;   // 131072 threads
    int n = g & 1023, k0 = (g >> 10) << 3;
    half8 h, l;
    #pragma unroll
    for (int e = 0; e < 8; ++e) {
        float val = Minv[(size_t)(k0 + e) * MOUT + n];
        _Float16 hh = (_Float16)val;
        h[e] = hh;
        l[e] = (_Float16)(val - (float)hh);
    }
    size_t off = swz32(n, k0);
    *(half8*)&Th[off] = h;
    *(half8*)&Tl[off] = l;
}

// ---------------------------------------------------------------------------
// wsh/wsl = 16x16-swizzled split-f16 of weight (dec path, unchanged).
// ---------------------------------------------------------------------------
__global__ __launch_bounds__(256) void split_w(const float* __restrict__ w,
                                               _Float16* __restrict__ wsh,
                                               _Float16* __restrict__ wsl) {
    int g = blockIdx.x * 256 + threadIdx.x;   // 65536 threads
    int n = g & 511, k0 = (g >> 9) << 3;
    half8 h, l;
    #pragma unroll
    for (int e = 0; e < 8; ++e) {
        float val = w[(size_t)(k0 + e) * NIN + n];
        _Float16 hh = (_Float16)val;
        h[e] = hh;
        l[e] = (_Float16)(val - (float)hh);
    }
    size_t off = swz(n, k0);
    *(half8*)&wsh[off] = h;
    *(half8*)&wsl[off] = l;
}

// ---------------------------------------------------------------------------
// adb = x @ w^T (fp32, once). Epilogue emits beff = adb as 32x32-swizzled h/l
// into buffer 0 (read by iteration 0).
// ---------------------------------------------------------------------------
__global__ __launch_bounds__(256) void gemm_adb(const float* __restrict__ x,
                                                const float* __restrict__ w,
                                                float* __restrict__ adb,
                                                _Float16* __restrict__ bh,
                                                _Float16* __restrict__ bl) {
    __shared__ float As[16][68];
    __shared__ float Bs[16][68];
    const int tid = threadIdx.x;
    const int i0 = (blockIdx.x >> 4) * 64, j0 = (blockIdx.x & 15) * 64;
    const int tx = tid & 15, ty = tid >> 4;
    const int lr = tid >> 2, lk = (tid & 3) << 2;
    float acc[4][4] = {};
    for (int k0 = 0; k0 < NIN; k0 += 16) {
        float4 a4 = *(const float4*)&x[(i0 + lr) * NIN + k0 + lk];
        As[lk + 0][lr] = a4.x; As[lk + 1][lr] = a4.y;
        As[lk + 2][lr] = a4.z; As[lk + 3][lr] = a4.w;
        float4 b4 = *(const float4*)&w[(j0 + lr) * NIN + k0 + lk];
        Bs[lk + 0][lr] = b4.x; Bs[lk + 1][lr] = b4.y;
        Bs[lk + 2][lr] = b4.z; Bs[lk + 3][lr] = b4.w;
        __syncthreads();
        #pragma unroll
        for (int kk = 0; kk < 16; ++kk) {
            float4 a_ = *(const float4*)&As[kk][ty << 2];
            float4 b_ = *(const float4*)&Bs[kk][tx << 2];
            #pragma unroll
            for (int r = 0; r < 4; ++r) {
                float av = r == 0 ? a_.x : r == 1 ? a_.y : r == 2 ? a_.z : a_.w;
                acc[r][0] = fmaf(av, b_.x, acc[r][0]);
                acc[r][1] = fmaf(av, b_.y, acc[r][1]);
                acc[r][2] = fmaf(av, b_.z, acc[r][2]);
                acc[r][3] = fmaf(av, b_.w, acc[r][3]);
            }
        }
        __syncthreads();
    }
    const int k4 = j0 + (tx << 2);
    #pragma unroll
    for (int r = 0; r < 4; ++r) {
        const int row = i0 + (ty << 2) + r;
        *(float4*)&adb[(size_t)row * MOUT + k4] =
            make_float4(acc[r][0], acc[r][1], acc[r][2], acc[r][3]);
        half4 h, l;
        #pragma unroll
        for (int e = 0; e < 4; ++e) {
            _Float16 hh = (_Float16)acc[r][e];
            h[e] = hh;
            l[e] = (_Float16)(acc[r][e] - (float)hh);
        }
        size_t off = swz32(row, k4);
        *(half4*)&bh[off] = h;
        *(half4*)&bl[off] = l;
    }
}

// ---------------------------------------------------------------------------
// FUSED persistent ADMM loop v4: 32x32x16 MFMA + ping-pong beff.
// 256 blocks x 512 threads (1/CU): 8 stripes (mt, 128 batch rows) x 32 nt
// (32 n each). Minv slice (32n x 1024k, h/l) = 128 KB LDS, loaded once.
// Wave (bt,kh): 32x32 tile (n x batch, swapped operands) x K-half; halves
// combine via padded LDS scratch as xk = p0 + p1. Lane owns 1 batch row x
// 16 n; treg/adbreg register-resident. beff double-buffered (read it&1,
// write the other) - removes the round-6 same-phase write/read race.
// ---------------------------------------------------------------------------
__global__ __launch_bounds__(512, 2)
void admm_loop(const float* __restrict__ adb, float* __restrict__ part,
               _Float16* __restrict__ bh0, _Float16* __restrict__ bl0,
               _Float16* __restrict__ bh1, _Float16* __restrict__ bl1,
               const _Float16* __restrict__ Th, const _Float16* __restrict__ Tl,
               float* __restrict__ enc, _Float16* __restrict__ ench,
               _Float16* __restrict__ encl, int* __restrict__ solved,
               int* __restrict__ bar) {
    const int bid = blockIdx.x;
    const int tid = threadIdx.x, lane = tid & 63;
    const int w = tid >> 6;                // wave 0..7
    const int bt = w >> 1;                 // batch tile 0..3
    const int kh = w & 1;                  // K-half
    const int mt = bid & 7, nt = bid >> 3;
    const int n0 = nt << 5, m0 = mt << 7;
    const int hn = lane >> 5;              // n-half selector
    const int brow = m0 + (bt << 5) + (lane & 31);
    const int btile = (mt << 2) + bt;      // beff 32-row tile

    __shared__ _Float16 Bs[128 * 512];     // 128 KB Minv slice: chunk=kc*2+hl
    __shared__ float sc[4][64][24];        // 24 KB k-half exchange (4-way pad)
    __shared__ int s_exit;

    // one-time Minv staging: 128 chunks of 1 KB (16 per wave)
    #pragma unroll
    for (int q = 0; q < 16; ++q) {
        const int chunk = (w << 4) + q;
        const int kc = chunk >> 1, hl = chunk & 1;
        const _Float16* src = (hl ? Tl : Th) +
            (((size_t)((nt << 6) + kc)) << 9) + ((size_t)lane << 3);
        __builtin_amdgcn_global_load_lds(
            (const __attribute__((address_space(1))) void*)src,
            (__attribute__((address_space(3))) void*)&Bs[(size_t)chunk << 9],
            16, 0, 0);
    }
    __syncthreads();

    int* gcnt = bar + (mt << 5);
    int* ggen = bar + (mt << 5) + 16;

    // register-resident state (meaningful in kh==0 waves):
    // lane's 16 n: n = n0 + 8*r4 + 4*hn + e   [C/D row map m74/m101]
    float treg[16] = {};
    float adbreg[16];
    #pragma unroll
    for (int r4 = 0; r4 < 4; ++r4) {
        const int nb = n0 + (r4 << 3) + (hn << 2);
        float4 a4 = *(const float4*)&adb[(size_t)brow * MOUT + nb];
        adbreg[(r4 << 2) + 0] = a4.x; adbreg[(r4 << 2) + 1] = a4.y;
        adbreg[(r4 << 2) + 2] = a4.z; adbreg[(r4 << 2) + 3] = a4.w;
    }
    bool sflag = false;

    for (int it = 0; it < MAX_ITERS; ++it) {
        const _Float16* rbh = (it & 1) ? bh1 : bh0;
        const _Float16* rbl = (it & 1) ? bl1 : bl0;
        _Float16* wbh = (it & 1) ? bh0 : bh1;
        _Float16* wbl = (it & 1) ? bl0 : bl1;

        // ============ PHASE A: 32x32x16 gemm (3 independent chains) ========
        floatx16 accA = {}, accB = {}, accC = {};
        const int kc0 = kh << 5;
        #pragma unroll 4
        for (int kc = kc0; kc < kc0 + 32; ++kc) {
            const size_t boff =
                (((size_t)(btile << 6) + kc) << 9) + ((size_t)lane << 3);
            const half8 bhf = *(const half8*)&rbh[boff];
            const half8 blf = *(const half8*)&rbl[boff];
            const half8 ah = *(const half8*)&Bs[((kc << 1) << 9) + (lane << 3)];
            const half8 al = *(const half8*)&Bs[(((kc << 1) | 1) << 9) + (lane << 3)];
            accA = __builtin_amdgcn_mfma_f32_32x32x16_f16(al, bhf, accA, 0, 0, 0);
            accB = __builtin_amdgcn_mfma_f32_32x32x16_f16(ah, blf, accB, 0, 0, 0);
            accC = __builtin_amdgcn_mfma_f32_32x32x16_f16(ah, bhf, accC, 0, 0, 0);
        }
        if (kh) {   // publish k-half 1 partial
            #pragma unroll
            for (int r4 = 0; r4 < 4; ++r4) {
                float4 v;
                v.x = (accA[(r4 << 2) + 0] + accB[(r4 << 2) + 0]) + accC[(r4 << 2) + 0];
                v.y = (accA[(r4 << 2) + 1] + accB[(r4 << 2) + 1]) + accC[(r4 << 2) + 1];
                v.z = (accA[(r4 << 2) + 2] + accB[(r4 << 2) + 2]) + accC[(r4 << 2) + 2];
                v.w = (accA[(r4 << 2) + 3] + accB[(r4 << 2) + 3]) + accC[(r4 << 2) + 3];
                *(float4*)&sc[bt][lane][r4 << 2] = v;
            }
        }
        __syncthreads();

        // ============ fused update (kh==0 waves) ===========================
        float dx2 = 0.f, x2 = 0.f;
        if (kh == 0 && !sflag) {
            #pragma unroll
            for (int r4 = 0; r4 < 4; ++r4) {
                float4 p1 = *(const float4*)&sc[bt][lane][r4 << 2];
                float pa[4] = {p1.x, p1.y, p1.z, p1.w};
                half4 h, l;
                #pragma unroll
                for (int e = 0; e < 4; ++e) {
                    const int r = (r4 << 2) + e;
                    float s0 = (accA[r] + accB[r]) + accC[r];
                    float xk = s0 + pa[e];            // p0 + p1 (ref order)
                    float t_ = treg[r];
                    float vprev = shrinkf(t_);
                    float uu = t_ - vprev;
                    float tn = xk + uu;               // = u + xk
                    float vv = shrinkf(tn);
                    float un = tn - vv;               // u_new
                    float d = vv - vprev;
                    dx2 += d * d;
                    x2 += vv * vv;
                    treg[r] = tn;
                    float nb_ = (adbreg[r] + vv) - un;
                    _Float16 hh = (_Float16)nb_;
                    h[e] = hh;
                    l[e] = (_Float16)(nb_ - (float)hh);
                }
                size_t off = swz32(brow, n0 + (r4 << 3) + (hn << 2));
                *(half4*)&wbh[off] = h;
                *(half4*)&wbl[off] = l;
            }
            // row partial over block's 32 n: lane ^ 32 holds the other n-half
            dx2 += __shfl_xor(dx2, 32);
            x2  += __shfl_xor(x2, 32);
            if (hn == 0)
                *(float2*)&part[(((size_t)brow << 5) | nt) << 1] =
                    make_float2(dx2, x2);
        }
        gbar32(gcnt, ggen, 2 * it + 1);

        // ============ PHASE B: norm finish + freeze (4 rows/block) =========
        if (w < 4) {
            const int urow = m0 + (nt << 2) + w;
            if (!((volatile const int*)solved)[urow]) {
                float2 p = *(const float2*)
                    &part[(((size_t)urow << 5) | (lane & 31)) << 1];
                float rdx = p.x, rx = p.y;
                #pragma unroll
                for (int off = 16; off; off >>= 1) {
                    rdx += __shfl_xor(rdx, off);
                    rx  += __shfl_xor(rx, off);
                }
                if (rdx < TOLF * TOLF * rx) {   // x2==0 -> false (NaN sem.)
                    if (lane == 0) ((volatile int*)solved)[urow] = 1;
                }
            }
        }
        gbar32(gcnt, ggen, 2 * it + 2);

        // refresh frozen mask + stripe-uniform exact early exit
        sflag = ((volatile const int*)solved)[brow] != 0;
        if (tid == 0) s_exit = 0;
        __syncthreads();
        if (kh == 0 && !sflag && lane < 32) s_exit = 1;  // benign race
        __syncthreads();
        if (s_exit == 0) break;
    }

    // ============ final flush: enc = shrink(t_frozen) for solved rows ======
    if (kh == 0 && sflag) {
        #pragma unroll
        for (int r4 = 0; r4 < 4; ++r4) {
            const int nb = n0 + (r4 << 3) + (hn << 2);
            float va[4]; half4 h, l;
            #pragma unroll
            for (int e = 0; e < 4; ++e) {
                float vv = shrinkf(treg[(r4 << 2) + e]);
                va[e] = vv;
                _Float16 hh = (_Float16)vv;
                h[e] = hh;
                l[e] = (_Float16)(vv - (float)hh);
            }
            *(float4*)&enc[(size_t)brow * MOUT + nb] =
                make_float4(va[0], va[1], va[2], va[3]);
            size_t off = swz(brow, nb);        // dec path keeps 16x16 swizzle
            *(half4*)&ench[off] = h;
            *(half4*)&encl[off] = l;
        }
    }
}

// ---------------------------------------------------------------------------
// dec = enc @ w, split-f16 MFMA (16x16 path), runs ONCE. Unchanged.
// ---------------------------------------------------------------------------
__global__ __launch_bounds__(256, 2)
void mfma_dec(const _Float16* __restrict__ Ahg, const _Float16* __restrict__ Alg,
              const _Float16* __restrict__ Bhg, const _Float16* __restrict__ Blg,
              float* __restrict__ out) {
    constexpr int NSTR = NIN;              // 512
    constexpr int NT = NSTR / 128;         // 4
    const int bid = blockIdx.x;
    const int c = bid & 7, t = bid >> 3;
    const int mt = t / NT, nt = t % NT;
    const int tid = threadIdx.x, lane = tid & 63;

    __shared__ _Float16 Ash[64 * 512];     // 64 KB

    const int wv = tid >> 6;
    const int wm = (tid >> 7) & 1, wn = (tid >> 6) & 1;
    const int kf0 = c << 2;

    #pragma unroll
    for (int i = 0; i < 16; ++i) {
        const int chunk = (wv << 4) + i;
        const int rt = chunk >> 3, kc = (chunk >> 1) & 3, hl = chunk & 1;
        const _Float16* src = (hl ? Alg : Ahg) +
            ((((size_t)((mt << 3) + rt) * 32 + kf0 + kc) << 9) + ((size_t)lane << 3));
        __builtin_amdgcn_global_load_lds(
            (const __attribute__((address_space(1))) void*)src,
            (__attribute__((address_space(3))) void*)&Ash[(size_t)chunk << 9],
            16, 0, 0);
    }
    __syncthreads();

    const int ct0 = nt * 8 + (wn << 2);
    const _Float16* pBh = Bhg + ((((size_t)ct0 * 32 + kf0) * 64 + lane) << 3);
    const _Float16* pBl = Blg + ((((size_t)ct0 * 32 + kf0) * 64 + lane) << 3);

    floatx4 acc[4][4] = {};
    #pragma unroll
    for (int s = 0; s < 4; ++s) {
        half8 bhf[4], blf[4];
        #pragma unroll
        for (int j = 0; j < 4; ++j) {
            bhf[j] = *(const half8*)(pBh + ((size_t)j << 14) + ((size_t)s << 9));
            blf[j] = *(const half8*)(pBl + ((size_t)j << 14) + ((size_t)s << 9));
        }
        half8 ah[4], al[4];
        #pragma unroll
        for (int i = 0; i < 4; ++i) {
            const int rt = (wm << 2) + i;
            ah[i] = *(const half8*)&Ash[((((rt << 2) + s) << 1) << 9) + (lane << 3)];
            al[i] = *(const half8*)&Ash[(((((rt << 2) + s) << 1) + 1) << 9) + (lane << 3)];
        }
        #pragma unroll
        for (int i = 0; i < 4; ++i)
            #pragma unroll
            for (int j = 0; j < 4; ++j) {
                acc[i][j] = __builtin_amdgcn_mfma_f32_16x16x32_f16(
                    ah[i], blf[j], acc[i][j], 0, 0, 0);
                acc[i][j] = __builtin_amdgcn_mfma_f32_16x16x32_f16(
                    al[i], bhf[j], acc[i][j], 0, 0, 0);
                acc[i][j] = __builtin_amdgcn_mfma_f32_16x16x32_f16(
                    ah[i], bhf[j], acc[i][j], 0, 0, 0);
            }
    }

    const int orow = (lane >> 4) << 2;
    #pragma unroll
    for (int i = 0; i < 4; ++i) {
        const int gr = (mt << 7) + (wm << 6) + (i << 4) + orow;
        #pragma unroll
        for (int j = 0; j < 4; ++j) {
            const int gc = nt * 128 + (wn << 6) + (j << 4) + (lane & 15);
            #pragma unroll
            for (int r = 0; r < 4; ++r)
                atomicAdd(&out[(size_t)(gr + r) * NSTR + gc], acc[i][j][r]);
        }
    }
}

// ---------------------------------------------------------------------------
extern "C" void kernel_launch(void* const* d_in, const int* in_sizes, int n_in,
                              void* d_out, int out_size, void* d_ws, size_t ws_size,
                              hipStream_t stream) {
    const float* x    = (const float*)d_in[0];
    const float* w    = (const float*)d_in[1];
    const float* Minv = (const float*)d_in[2];

    float* enc = (float*)d_out;          // encoded: 1024*1024
    float* dec = enc + MM;               // decoded: 1024*512

    // ws (floats): adb MM | beff buf1 (bh1,bl1 = MM floats) | part 2*MM |
    // halves: bh0,bl0,Th,Tl,ench,encl MM, wsh,wsl MM/2 | solved + barriers.
    float* ws  = (float*)d_ws;
    float* adb = ws;
    _Float16* bh1 = (_Float16*)(ws + (size_t)MM);   // ping-pong buffer 1
    _Float16* bl1 = bh1 + (size_t)MM;
    float* part = ws + 2 * (size_t)MM;              // norm partials

    _Float16* bh0  = (_Float16*)(ws + 4 * (size_t)MM);
    _Float16* bl0  = bh0 + (size_t)MM;
    _Float16* Th   = bl0 + (size_t)MM;
    _Float16* Tl   = Th + (size_t)MM;
    _Float16* ench = Tl + (size_t)MM;
    _Float16* encl = ench + (size_t)MM;
    _Float16* wsh  = encl + (size_t)MM;
    _Float16* wsl  = wsh + (size_t)(NIN * MOUT);
    int* solved    = (int*)(wsl + (size_t)(NIN * MOUT));
    int* bar       = solved + 1088;      // 8 stripes x 32 ints (128 B) apart

    zero_init<<<(MM + 255) / 256, 256, 0, stream>>>((float*)bh1, enc, dec,
                                                    (float*)ench, (float*)encl,
                                                    solved);
    split_minv<<<512, 256, 0, stream>>>(Minv, Th, Tl);
    split_w<<<256, 256, 0, stream>>>(w, wsh, wsl);
    gemm_adb<<<256, 256, 0, stream>>>(x, w, adb, bh0, bl0);

    void* cargs[] = {(void*)&adb, (void*)&part,
                     (void*)&bh0, (void*)&bl0, (void*)&bh1, (void*)&bl1,
                     (void*)&Th,  (void*)&Tl,
                     (void*)&enc, (void*)&ench, (void*)&encl, (void*)&solved,
                     (void*)&bar};
    // Cooperative launch used ONLY as a co-residency guarantee (deadlock
    // safety for the spin barriers); no grid.sync() is ever called.
    hipLaunchCooperativeKernel(reinterpret_cast<void*>(admm_loop),
                               dim3(256), dim3(512), cargs, 0, stream);

    mfma_dec<<<256, 256, 0, stream>>>(ench, encl, wsh, wsl, dec);
}

// Round 8
// 1040.628 us; speedup vs baseline: 2.2994x; 1.2387x over previous
//
#include <hip/hip_runtime.h>

typedef _Float16 half8 __attribute__((ext_vector_type(8)));
typedef _Float16 half4 __attribute__((ext_vector_type(4)));
typedef float floatx4 __attribute__((ext_vector_type(4)));
typedef float floatx16 __attribute__((ext_vector_type(16)));

static constexpr int BATCH = 1024;
static constexpr int NIN   = 512;    // in_features
static constexpr int MOUT  = 1024;   // out_features
static constexpr float LAMBD = 0.2f;
static constexpr float TOLF  = 1e-4f;
static constexpr int MAX_ITERS = 100;
static constexpr int MM = BATCH * MOUT;   // 1M elements

// 16x16x32 fragment swizzle (dec path): lane=(idx&15)|(((k>>3)&3)<<4)
__device__ __forceinline__ size_t swz(int idx, int k) {
    return ((((size_t)(idx >> 4) * 32 + (k >> 5)) * 64 +
             ((idx & 15) | (((k >> 3) & 3) << 4))) << 3) + (k & 7);
}

// 32x32x16 fragment swizzle (iteration GEMM): 64-lane chunk per (tile32, kc16),
// lane = (idx&31) | (((k>>3)&1)<<5), elem = k&7  [HW-validated round 7]
__device__ __forceinline__ size_t swz32(int idx, int k) {
    return ((((size_t)(idx >> 5) * 64 + (k >> 4)) * 64 +
             ((idx & 31) | (((k >> 3) & 1) << 5))) << 3) + (k & 7);
}

__device__ __forceinline__ float shrinkf(float t) {
    float a = fabsf(t) - LAMBD;
    return a > 0.f ? copysignf(a, t) : 0.f;
}

// ---------------------------------------------------------------------------
// XCD-local 32-block barrier (rounds 3-7 proven). Stripe = one XCD (bid%8):
// stores L2-visible after vmcnt drain (write-through L1); one device-scope
// RMW arrive; relaxed spin; L1-only invalidate. ONE barrier per iteration.
// ---------------------------------------------------------------------------
__device__ __forceinline__ void gbar32(int* cnt, int* gen, int seq) {
    __syncthreads();
    if (threadIdx.x == 0) {
        int old = atomicAdd(cnt, 1);
        if (old == seq * 32 - 1) {
            __hip_atomic_store(gen, seq, __ATOMIC_RELAXED,
                               __HIP_MEMORY_SCOPE_AGENT);
        } else {
            while (__hip_atomic_load(gen, __ATOMIC_RELAXED,
                                     __HIP_MEMORY_SCOPE_AGENT) < seq)
                __builtin_amdgcn_s_sleep(1);
        }
    }
    __syncthreads();
    asm volatile("buffer_inv sc0" ::: "memory");
}

// ---------------------------------------------------------------------------
__global__ __launch_bounds__(256) void zero_init(float* t, float* enc,
                                                 float* dec, float* ench_f,
                                                 float* encl_f, int* solved) {
    int i = blockIdx.x * 256 + threadIdx.x;
    if (i < MM) { t[i] = 0.f; enc[i] = 0.f; }
    if (i < MM / 2) { dec[i] = 0.f; ench_f[i] = 0.f; encl_f[i] = 0.f; }
    if (i < 4096) solved[i] = 0;   // barrier words live at solved+1088
}

// ---------------------------------------------------------------------------
// Th/Tl = 32x32-fragment-swizzled split-f16 of Minv (idx=n, k over 1024).
// ---------------------------------------------------------------------------
__global__ __launch_bounds__(256) void split_minv(const float* __restrict__ Minv,
                                                  _Float16* __restrict__ Th,
                                                  _Float16* __restrict__ Tl) {
    int g = blockIdx.x * 256 + threadIdx.x;   // 131072 threads
    int n = g & 1023, k0 = (g >> 10) << 3;
    half8 h, l;
    #pragma unroll
    for (int e = 0; e < 8; ++e) {
        float val = Minv[(size_t)(k0 + e) * MOUT + n];
        _Float16 hh = (_Float16)val;
        h[e] = hh;
        l[e] = (_Float16)(val - (float)hh);
    }
    size_t off = swz32(n, k0);
    *(half8*)&Th[off] = h;
    *(half8*)&Tl[off] = l;
}

// ---------------------------------------------------------------------------
// wsh/wsl = 16x16-swizzled split-f16 of weight (dec path).
// ---------------------------------------------------------------------------
__global__ __launch_bounds__(256) void split_w(const float* __restrict__ w,
                                               _Float16* __restrict__ wsh,
                                               _Float16* __restrict__ wsl) {
    int g = blockIdx.x * 256 + threadIdx.x;   // 65536 threads
    int n = g & 511, k0 = (g >> 9) << 3;
    half8 h, l;
    #pragma unroll
    for (int e = 0; e < 8; ++e) {
        float val = w[(size_t)(k0 + e) * NIN + n];
        _Float16 hh = (_Float16)val;
        h[e] = hh;
        l[e] = (_Float16)(val - (float)hh);
    }
    size_t off = swz(n, k0);
    *(half8*)&wsh[off] = h;
    *(half8*)&wsl[off] = l;
}

// ---------------------------------------------------------------------------
// adb = x @ w^T (fp32, once). Epilogue emits beff buffer 0 (32x32 swizzle).
// ---------------------------------------------------------------------------
__global__ __launch_bounds__(256) void gemm_adb(const float* __restrict__ x,
                                                const float* __restrict__ w,
                                                float* __restrict__ adb,
                                                _Float16* __restrict__ bh,
                                                _Float16* __restrict__ bl) {
    __shared__ float As[16][68];
    __shared__ float Bs[16][68];
    const int tid = threadIdx.x;
    const int i0 = (blockIdx.x >> 4) * 64, j0 = (blockIdx.x & 15) * 64;
    const int tx = tid & 15, ty = tid >> 4;
    const int lr = tid >> 2, lk = (tid & 3) << 2;
    float acc[4][4] = {};
    for (int k0 = 0; k0 < NIN; k0 += 16) {
        float4 a4 = *(const float4*)&x[(i0 + lr) * NIN + k0 + lk];
        As[lk + 0][lr] = a4.x; As[lk + 1][lr] = a4.y;
        As[lk + 2][lr] = a4.z; As[lk + 3][lr] = a4.w;
        float4 b4 = *(const float4*)&w[(j0 + lr) * NIN + k0 + lk];
        Bs[lk + 0][lr] = b4.x; Bs[lk + 1][lr] = b4.y;
        Bs[lk + 2][lr] = b4.z; Bs[lk + 3][lr] = b4.w;
        __syncthreads();
        #pragma unroll
        for (int kk = 0; kk < 16; ++kk) {
            float4 a_ = *(const float4*)&As[kk][ty << 2];
            float4 b_ = *(const float4*)&Bs[kk][tx << 2];
            #pragma unroll
            for (int r = 0; r < 4; ++r) {
                float av = r == 0 ? a_.x : r == 1 ? a_.y : r == 2 ? a_.z : a_.w;
                acc[r][0] = fmaf(av, b_.x, acc[r][0]);
                acc[r][1] = fmaf(av, b_.y, acc[r][1]);
                acc[r][2] = fmaf(av, b_.z, acc[r][2]);
                acc[r][3] = fmaf(av, b_.w, acc[r][3]);
            }
        }
        __syncthreads();
    }
    const int k4 = j0 + (tx << 2);
    #pragma unroll
    for (int r = 0; r < 4; ++r) {
        const int row = i0 + (ty << 2) + r;
        *(float4*)&adb[(size_t)row * MOUT + k4] =
            make_float4(acc[r][0], acc[r][1], acc[r][2], acc[r][3]);
        half4 h, l;
        #pragma unroll
        for (int e = 0; e < 4; ++e) {
            _Float16 hh = (_Float16)acc[r][e];
            h[e] = hh;
            l[e] = (_Float16)(acc[r][e] - (float)hh);
        }
        size_t off = swz32(row, k4);
        *(half4*)&bh[off] = h;
        *(half4*)&bl[off] = l;
    }
}

// ---------------------------------------------------------------------------
// FUSED persistent ADMM loop v5: ONE barrier/iter, decision hidden under GEMM.
// 256 blocks x 512 threads (1/CU): 8 stripes (mt, 128 rows) x 32 nt (32 n).
// Minv slice 128 KB LDS once. Wave (bt,kh): 32x32 tile x K-half; halves
// combine via conflict-free sc4 LDS. Convergence decision for iter it-1 is
// computed redundantly by EVERY block during iter it's GEMM (part buffer is
// ping-ponged so read-old/write-new is race-free), published in block-local
// sticky LDS mask sfroz[128]. No global solved array, no phase B, no 2nd
// barrier. Early exit: block-local ballot over sfroz (stripe-uniform).
// Rows converging at the final iteration: one post-loop decision pass.
// ---------------------------------------------------------------------------
__global__ __launch_bounds__(512, 1)
void admm_loop(const float* __restrict__ adb, float* __restrict__ part,
               _Float16* __restrict__ bh0, _Float16* __restrict__ bl0,
               _Float16* __restrict__ bh1, _Float16* __restrict__ bl1,
               const _Float16* __restrict__ Th, const _Float16* __restrict__ Tl,
               float* __restrict__ enc, _Float16* __restrict__ ench,
               _Float16* __restrict__ encl, int* __restrict__ bar) {
    const int bid = blockIdx.x;
    const int tid = threadIdx.x, lane = tid & 63;
    const int w = tid >> 6;                // wave 0..7
    const int bt = w >> 1;                 // batch tile 0..3
    const int kh = w & 1;                  // K-half
    const int mt = bid & 7, nt = bid >> 3;
    const int n0 = nt << 5, m0 = mt << 7;
    const int hn = lane >> 5;              // n-half selector
    const int brow = m0 + (bt << 5) + (lane & 31);
    const int btile = (mt << 2) + bt;      // beff 32-row tile

    __shared__ _Float16 Bs[128 * 512];     // 128 KB Minv slice: chunk=kc*2+hl
    __shared__ float4 sc4[4][4][64];       // 16 KB k-half exchange, lane-contig
    __shared__ unsigned char sfroz[128];   // sticky frozen mask (block-local)

    if (tid < 128) sfroz[tid] = 0;

    // one-time Minv staging: 128 chunks of 1 KB (16 per wave)
    #pragma unroll
    for (int q = 0; q < 16; ++q) {
        const int chunk = (w << 4) + q;
        const int kc = chunk >> 1, hl = chunk & 1;
        const _Float16* src = (hl ? Tl : Th) +
            (((size_t)((nt << 6) + kc)) << 9) + ((size_t)lane << 3);
        __builtin_amdgcn_global_load_lds(
            (const __attribute__((address_space(1))) void*)src,
            (__attribute__((address_space(3))) void*)&Bs[(size_t)chunk << 9],
            16, 0, 0);
    }
    __syncthreads();

    int* gcnt = bar + (mt << 5);
    int* ggen = bar + (mt << 5) + 16;

    // decision geometry: wave handles rows m0+w*16..+15; 4 lanes per row
    const int drow_l = (w << 4) + (lane >> 2);     // row-in-stripe 0..127
    const int dq = (lane & 3) << 3;                // first float2 idx (0..24)
    const float* dbase0 = part + ((((size_t)(m0 + drow_l)) << 6) + (dq << 1));

    // register-resident state (kh==0 waves): n = n0 + 8*r4 + 4*hn + e
    float treg[16] = {};
    float adbreg[16];
    #pragma unroll
    for (int r4 = 0; r4 < 4; ++r4) {
        const int nb = n0 + (r4 << 3) + (hn << 2);
        float4 a4 = *(const float4*)&adb[(size_t)brow * MOUT + nb];
        adbreg[(r4 << 2) + 0] = a4.x; adbreg[(r4 << 2) + 1] = a4.y;
        adbreg[(r4 << 2) + 2] = a4.z; adbreg[(r4 << 2) + 3] = a4.w;
    }

    int it = 0;
    for (; it < MAX_ITERS; ++it) {
        const _Float16* rbh = (it & 1) ? bh1 : bh0;
        const _Float16* rbl = (it & 1) ? bl1 : bl0;
        _Float16* wbh = (it & 1) ? bh0 : bh1;
        _Float16* wbl = (it & 1) ? bl0 : bl1;
        const int pw = it & 1;             // part write buffer

        // ---- issue decision loads (iter it-1 partials, buffer !pw) early
        float4 dp0, dp1, dp2, dp3;
        if (it) {
            const float* pb = dbase0 + ((size_t)(pw ^ 1) << 16);
            dp0 = *(const float4*)(pb + 0);
            dp1 = *(const float4*)(pb + 4);
            dp2 = *(const float4*)(pb + 8);
            dp3 = *(const float4*)(pb + 12);
        }

        // ============ PHASE A: 32x32x16 gemm (3 independent chains) ========
        floatx16 accA = {}, accB = {}, accC = {};
        const int kc0 = kh << 5;
        #pragma unroll 4
        for (int kc = kc0; kc < kc0 + 32; ++kc) {
            const size_t boff =
                (((size_t)(btile << 6) + kc) << 9) + ((size_t)lane << 3);
            const half8 bhf = *(const half8*)&rbh[boff];
            const half8 blf = *(const half8*)&rbl[boff];
            const half8 ah = *(const half8*)&Bs[((kc << 1) << 9) + (lane << 3)];
            const half8 al = *(const half8*)&Bs[(((kc << 1) | 1) << 9) + (lane << 3)];
            accA = __builtin_amdgcn_mfma_f32_32x32x16_f16(al, bhf, accA, 0, 0, 0);
            accB = __builtin_amdgcn_mfma_f32_32x32x16_f16(ah, blf, accB, 0, 0, 0);
            accC = __builtin_amdgcn_mfma_f32_32x32x16_f16(ah, bhf, accC, 0, 0, 0);
        }
        if (kh) {   // publish k-half-1 partial (conflict-free layout)
            #pragma unroll
            for (int r4 = 0; r4 < 4; ++r4) {
                float4 v;
                v.x = (accA[(r4 << 2) + 0] + accB[(r4 << 2) + 0]) + accC[(r4 << 2) + 0];
                v.y = (accA[(r4 << 2) + 1] + accB[(r4 << 2) + 1]) + accC[(r4 << 2) + 1];
                v.z = (accA[(r4 << 2) + 2] + accB[(r4 << 2) + 2]) + accC[(r4 << 2) + 2];
                v.w = (accA[(r4 << 2) + 3] + accB[(r4 << 2) + 3]) + accC[(r4 << 2) + 3];
                sc4[bt][r4][lane] = v;
            }
        }

        // ---- decision reduce for iter it-1 (hidden under GEMM latency)
        if (it) {
            float rdx = ((dp0.x + dp0.z) + (dp1.x + dp1.z)) +
                        ((dp2.x + dp2.z) + (dp3.x + dp3.z));
            float rx  = ((dp0.y + dp0.w) + (dp1.y + dp1.w)) +
                        ((dp2.y + dp2.w) + (dp3.y + dp3.w));
            rdx += __shfl_xor(rdx, 1); rdx += __shfl_xor(rdx, 2);
            rx  += __shfl_xor(rx, 1);  rx  += __shfl_xor(rx, 2);
            if (rdx < TOLF * TOLF * rx && (lane & 3) == 0)
                sfroz[drow_l] = 1;         // sticky set, never cleared
        }
        __syncthreads();                   // publishes sc4 AND sfroz

        // ---- stripe-uniform exact early exit (block-local ballot)
        bool f0 = sfroz[lane] != 0, f1 = sfroz[64 + lane] != 0;
        if ((__ballot(f0) & __ballot(f1)) == ~0ull) break;

        // ============ fused update (kh==0 waves, active rows) ==============
        const bool sflag = sfroz[(bt << 5) + (lane & 31)] != 0;
        if (kh == 0 && !sflag) {
            float dx2 = 0.f, x2 = 0.f;
            #pragma unroll
            for (int r4 = 0; r4 < 4; ++r4) {
                float4 p1 = sc4[bt][r4][lane];
                float pa[4] = {p1.x, p1.y, p1.z, p1.w};
                half4 h, l;
                #pragma unroll
                for (int e = 0; e < 4; ++e) {
                    const int r = (r4 << 2) + e;
                    float s0 = (accA[r] + accB[r]) + accC[r];
                    float xk = s0 + pa[e];            // p0 + p1 (ref order)
                    float t_ = treg[r];
                    float vprev = shrinkf(t_);
                    float uu = t_ - vprev;
                    float tn = xk + uu;               // = u + xk
                    float vv = shrinkf(tn);
                    float un = tn - vv;               // u_new
                    float d = vv - vprev;
                    dx2 += d * d;
                    x2 += vv * vv;
                    treg[r] = tn;
                    float nb_ = (adbreg[r] + vv) - un;
                    _Float16 hh = (_Float16)nb_;
                    h[e] = hh;
                    l[e] = (_Float16)(nb_ - (float)hh);
                }
                size_t off = swz32(brow, n0 + (r4 << 3) + (hn << 2));
                *(half4*)&wbh[off] = h;
                *(half4*)&wbl[off] = l;
            }
            // row partial over block's 32 n: lane^32 holds the other n-half
            dx2 += __shfl_xor(dx2, 32);
            x2  += __shfl_xor(x2, 32);
            if (hn == 0)
                *(float2*)&part[(((size_t)pw << 16) +
                                 (((size_t)brow) << 6) + ((size_t)nt << 1))] =
                    make_float2(dx2, x2);
        }
        gbar32(gcnt, ggen, it + 1);
    }

    // ---- final pending decision (rows converging at the last iteration)
    if (it == MAX_ITERS) {
        const float* pb = dbase0 + ((size_t)((MAX_ITERS - 1) & 1) << 16);
        float4 dp0 = *(const float4*)(pb + 0);
        float4 dp1 = *(const float4*)(pb + 4);
        float4 dp2 = *(const float4*)(pb + 8);
        float4 dp3 = *(const float4*)(pb + 12);
        float rdx = ((dp0.x + dp0.z) + (dp1.x + dp1.z)) +
                    ((dp2.x + dp2.z) + (dp3.x + dp3.z));
        float rx  = ((dp0.y + dp0.w) + (dp1.y + dp1.w)) +
                    ((dp2.y + dp2.w) + (dp3.y + dp3.w));
        rdx += __shfl_xor(rdx, 1); rdx += __shfl_xor(rdx, 2);
        rx  += __shfl_xor(rx, 1);  rx  += __shfl_xor(rx, 2);
        if (rdx < TOLF * TOLF * rx && (lane & 3) == 0)
            sfroz[drow_l] = 1;
        __syncthreads();
    }

    // ============ final flush: enc = shrink(t_frozen) for solved rows ======
    if (kh == 0 && sfroz[(bt << 5) + (lane & 31)]) {
        #pragma unroll
        for (int r4 = 0; r4 < 4; ++r4) {
            const int nb = n0 + (r4 << 3) + (hn << 2);
            float va[4]; half4 h, l;
            #pragma unroll
            for (int e = 0; e < 4; ++e) {
                float vv = shrinkf(treg[(r4 << 2) + e]);
                va[e] = vv;
                _Float16 hh = (_Float16)vv;
                h[e] = hh;
                l[e] = (_Float16)(vv - (float)hh);
            }
            *(float4*)&enc[(size_t)brow * MOUT + nb] =
                make_float4(va[0], va[1], va[2], va[3]);
            size_t off = swz(brow, nb);        // dec path keeps 16x16 swizzle
            *(half4*)&ench[off] = h;
            *(half4*)&encl[off] = l;
        }
    }
}

// ---------------------------------------------------------------------------
// dec = enc @ w, split-f16 MFMA (16x16 path), runs ONCE. Unchanged.
// ---------------------------------------------------------------------------
__global__ __launch_bounds__(256, 2)
void mfma_dec(const _Float16* __restrict__ Ahg, const _Float16* __restrict__ Alg,
              const _Float16* __restrict__ Bhg, const _Float16* __restrict__ Blg,
              float* __restrict__ out) {
    constexpr int NSTR = NIN;              // 512
    constexpr int NT = NSTR / 128;         // 4
    const int bid = blockIdx.x;
    const int c = bid & 7, t = bid >> 3;
    const int mt = t / NT, nt = t % NT;
    const int tid = threadIdx.x, lane = tid & 63;

    __shared__ _Float16 Ash[64 * 512];     // 64 KB

    const int wv = tid >> 6;
    const int wm = (tid >> 7) & 1, wn = (tid >> 6) & 1;
    const int kf0 = c << 2;

    #pragma unroll
    for (int i = 0; i < 16; ++i) {
        const int chunk = (wv << 4) + i;
        const int rt = chunk >> 3, kc = (chunk >> 1) & 3, hl = chunk & 1;
        const _Float16* src = (hl ? Alg : Ahg) +
            ((((size_t)((mt << 3) + rt) * 32 + kf0 + kc) << 9) + ((size_t)lane << 3));
        __builtin_amdgcn_global_load_lds(
            (const __attribute__((address_space(1))) void*)src,
            (__attribute__((address_space(3))) void*)&Ash[(size_t)chunk << 9],
            16, 0, 0);
    }
    __syncthreads();

    const int ct0 = nt * 8 + (wn << 2);
    const _Float16* pBh = Bhg + ((((size_t)ct0 * 32 + kf0) * 64 + lane) << 3);
    const _Float16* pBl = Blg + ((((size_t)ct0 * 32 + kf0) * 64 + lane) << 3);

    floatx4 acc[4][4] = {};
    #pragma unroll
    for (int s = 0; s < 4; ++s) {
        half8 bhf[4], blf[4];
        #pragma unroll
        for (int j = 0; j < 4; ++j) {
            bhf[j] = *(const half8*)(pBh + ((size_t)j << 14) + ((size_t)s << 9));
            blf[j] = *(const half8*)(pBl + ((size_t)j << 14) + ((size_t)s << 9));
        }
        half8 ah[4], al[4];
        #pragma unroll
        for (int i = 0; i < 4; ++i) {
            const int rt = (wm << 2) + i;
            ah[i] = *(const half8*)&Ash[((((rt << 2) + s) << 1) << 9) + (lane << 3)];
            al[i] = *(const half8*)&Ash[(((((rt << 2) + s) << 1) + 1) << 9) + (lane << 3)];
        }
        #pragma unroll
        for (int i = 0; i < 4; ++i)
            #pragma unroll
            for (int j = 0; j < 4; ++j) {
                acc[i][j] = __builtin_amdgcn_mfma_f32_16x16x32_f16(
                    ah[i], blf[j], acc[i][j], 0, 0, 0);
                acc[i][j] = __builtin_amdgcn_mfma_f32_16x16x32_f16(
                    al[i], bhf[j], acc[i][j], 0, 0, 0);
                acc[i][j] = __builtin_amdgcn_mfma_f32_16x16x32_f16(
                    ah[i], bhf[j], acc[i][j], 0, 0, 0);
            }
    }

    const int orow = (lane >> 4) << 2;
    #pragma unroll
    for (int i = 0; i < 4; ++i) {
        const int gr = (mt << 7) + (wm << 6) + (i << 4) + orow;
        #pragma unroll
        for (int j = 0; j < 4; ++j) {
            const int gc = nt * 128 + (wn << 6) + (j << 4) + (lane & 15);
            #pragma unroll
            for (int r = 0; r < 4; ++r)
                atomicAdd(&out[(size_t)(gr + r) * NSTR + gc], acc[i][j][r]);
        }
    }
}

// ---------------------------------------------------------------------------
extern "C" void kernel_launch(void* const* d_in, const int* in_sizes, int n_in,
                              void* d_out, int out_size, void* d_ws, size_t ws_size,
                              hipStream_t stream) {
    const float* x    = (const float*)d_in[0];
    const float* w    = (const float*)d_in[1];
    const float* Minv = (const float*)d_in[2];

    float* enc = (float*)d_out;          // encoded: 1024*1024
    float* dec = enc + MM;               // decoded: 1024*512

    // ws (floats): adb MM | beff buf1 (bh1,bl1) | part 2x256KB (in 2*MM) |
    // halves: bh0,bl0,Th,Tl,ench,encl MM, wsh,wsl MM/2 | barriers.
    float* ws  = (float*)d_ws;
    float* adb = ws;
    _Float16* bh1 = (_Float16*)(ws + (size_t)MM);   // ping-pong buffer 1
    _Float16* bl1 = bh1 + (size_t)MM;
    float* part = ws + 2 * (size_t)MM;              // 2 x [1024][32] float2

    _Float16* bh0  = (_Float16*)(ws + 4 * (size_t)MM);
    _Float16* bl0  = bh0 + (size_t)MM;
    _Float16* Th   = bl0 + (size_t)MM;
    _Float16* Tl   = Th + (size_t)MM;
    _Float16* ench = Tl + (size_t)MM;
    _Float16* encl = ench + (size_t)MM;
    _Float16* wsh  = encl + (size_t)MM;
    _Float16* wsl  = wsh + (size_t)(NIN * MOUT);
    int* solved    = (int*)(wsl + (size_t)(NIN * MOUT));
    int* bar       = solved + 1088;      // 8 stripes x 32 ints (128 B) apart

    zero_init<<<(MM + 255) / 256, 256, 0, stream>>>((float*)bh1, enc, dec,
                                                    (float*)ench, (float*)encl,
                                                    solved);
    split_minv<<<512, 256, 0, stream>>>(Minv, Th, Tl);
    split_w<<<256, 256, 0, stream>>>(w, wsh, wsl);
    gemm_adb<<<256, 256, 0, stream>>>(x, w, adb, bh0, bl0);

    void* cargs[] = {(void*)&adb, (void*)&part,
                     (void*)&bh0, (void*)&bl0, (void*)&bh1, (void*)&bl1,
                     (void*)&Th,  (void*)&Tl,
                     (void*)&enc, (void*)&ench, (void*)&encl, (void*)&bar};
    // Cooperative launch used ONLY as a co-residency guarantee (deadlock
    // safety for the spin barriers); no grid.sync() is ever called.
    hipLaunchCooperativeKernel(reinterpret_cast<void*>(admm_loop),
                               dim3(256), dim3(512), cargs, 0, stream);

    mfma_dec<<<256, 256, 0, stream>>>(ench, encl, wsh, wsl, dec);
}